// Round 1
// baseline (4039.322 us; speedup 1.0000x reference)
//
#include <hip/hip_runtime.h>
#include <cstddef>

// ============================================================================
// AlexCapsNet CIFAR-100 forward, fp32 baseline (round 0: correctness + sane tiling)
// Pipeline: conv1(3->96,p1)+relu -> pool -> conv2(96->256,p1)+relu -> pool ->
// conv3(256->384,p1)+relu -> pcaps(384->256,p0) -> squash8 ->
// 3x dynamic routing (recompute x_hat, never materialized) -> fc1+relu -> fc2+relu -> fc3
// ============================================================================

// ---------- conv1: direct 3->96 k3 s1 p1 + relu ----------
__global__ __launch_bounds__(256) void conv1_k(
    const float* __restrict__ x, const float* __restrict__ wt,
    const float* __restrict__ bias, float* __restrict__ out)
{
  int idx = blockIdx.x * 256 + threadIdx.x;          // [b,co,h,w] over 128*96*32*32
  int w = idx & 31, h = (idx >> 5) & 31;
  int t2 = idx >> 10;
  int co = t2 % 96, b = t2 / 96;
  float acc = bias[co];
  #pragma unroll
  for (int ci = 0; ci < 3; ++ci) {
    const float* xp = x + ((size_t)(b * 3 + ci) << 10);
    const float* wp = wt + (size_t)(co * 3 + ci) * 9;
    #pragma unroll
    for (int dh = 0; dh < 3; ++dh) {
      int ih = h + dh - 1;
      if (ih < 0 || ih > 31) continue;
      #pragma unroll
      for (int dw = 0; dw < 3; ++dw) {
        int iw = w + dw - 1;
        if (iw < 0 || iw > 31) continue;
        acc += xp[(ih << 5) + iw] * wp[dh * 3 + dw];
      }
    }
  }
  out[idx] = fmaxf(acc, 0.f);
}

// ---------- maxpool k3 s2 p1 (torch semantics) ----------
__global__ __launch_bounds__(256) void maxpool_k(
    const float* __restrict__ in, float* __restrict__ out, int H)
{
  int Ho = H >> 1;
  int idx = blockIdx.x * 256 + threadIdx.x;          // [bc, ho, wo]
  int wo = idx % Ho;
  int t2 = idx / Ho;
  int ho = t2 % Ho;
  int bc = t2 / Ho;
  const float* ip = in + (size_t)bc * H * H;
  float m = -3.4e38f;
  #pragma unroll
  for (int dh = 0; dh < 3; ++dh) {
    int ih = 2 * ho - 1 + dh;
    if (ih < 0 || ih >= H) continue;
    #pragma unroll
    for (int dw = 0; dw < 3; ++dw) {
      int iw = 2 * wo - 1 + dw;
      if (iw < 0 || iw >= H) continue;
      m = fmaxf(m, ip[ih * H + iw]);
    }
  }
  out[idx] = m;
}

// ---------- tiled direct conv k3 s1 p1 + relu (conv2 / conv3) ----------
// block = H*H threads, one (b, co-group) per block. Input tile staged in LDS
// per ci; 9 neighbor regs reused across NCO scalar-loaded weight sets.
template <int CI, int H, int NCO>
__global__ __launch_bounds__(H * H) void convk(
    const float* __restrict__ in, const float* __restrict__ wt,
    const float* __restrict__ bias, float* __restrict__ out, int CO)
{
  constexpr int HP = H + 2;
  __shared__ float tile[HP * HP];
  int cog = blockIdx.x, b = blockIdx.y;
  int t = threadIdx.x;
  int tx = t % H, ty = t / H;
  int co0 = cog * NCO;
  float acc[NCO];
  #pragma unroll
  for (int j = 0; j < NCO; ++j) acc[j] = bias[co0 + j];
  for (int ci = 0; ci < CI; ++ci) {
    __syncthreads();
    const float* ip = in + ((size_t)b * CI + ci) * (H * H);
    for (int l = t; l < HP * HP; l += H * H) {
      int r = l / HP - 1, cc = l % HP - 1;
      tile[l] = (r >= 0 && r < H && cc >= 0 && cc < H) ? ip[r * H + cc] : 0.f;
    }
    __syncthreads();
    float rg[9];
    #pragma unroll
    for (int dh = 0; dh < 3; ++dh)
      #pragma unroll
      for (int dw = 0; dw < 3; ++dw)
        rg[dh * 3 + dw] = tile[(ty + dh) * HP + tx + dw];
    const float* wp = wt + ((size_t)co0 * CI + ci) * 9;
    #pragma unroll
    for (int j = 0; j < NCO; ++j) {
      const float* wj = wp + (size_t)j * CI * 9;   // uniform address -> s_load
      float a = acc[j];
      #pragma unroll
      for (int k = 0; k < 9; ++k) a += rg[k] * wj[k];
      acc[j] = a;
    }
  }
  #pragma unroll
  for (int j = 0; j < NCO; ++j)
    out[((size_t)b * CO + co0 + j) * (H * H) + t] = fmaxf(acc[j], 0.f);
}

// ---------- primary caps conv: 384->256 k3 s1 p0, NO relu ----------
__global__ __launch_bounds__(64) void pcaps_k(
    const float* __restrict__ in, const float* __restrict__ wt,
    const float* __restrict__ bias, float* __restrict__ out)
{
  __shared__ float tile[64];
  const int NCO = 16;
  int cog = blockIdx.x, b = blockIdx.y, t = threadIdx.x;
  int co0 = cog * NCO;
  int tx = t % 6, ty = t / 6;                      // valid for t < 36
  float acc[NCO];
  #pragma unroll
  for (int j = 0; j < NCO; ++j) acc[j] = bias[co0 + j];
  for (int ci = 0; ci < 384; ++ci) {
    __syncthreads();
    tile[t] = in[((size_t)b * 384 + ci) * 64 + t];
    __syncthreads();
    if (t < 36) {
      float rg[9];
      #pragma unroll
      for (int dh = 0; dh < 3; ++dh)
        #pragma unroll
        for (int dw = 0; dw < 3; ++dw)
          rg[dh * 3 + dw] = tile[(ty + dh) * 8 + tx + dw];
      const float* wp = wt + ((size_t)co0 * 384 + ci) * 9;
      #pragma unroll
      for (int j = 0; j < NCO; ++j) {
        const float* wj = wp + (size_t)j * 384 * 9;
        float a = acc[j];
        #pragma unroll
        for (int k = 0; k < 9; ++k) a += rg[k] * wj[k];
        acc[j] = a;
      }
    }
  }
  if (t < 36) {
    #pragma unroll
    for (int j = 0; j < NCO; ++j)
      out[((size_t)b * 256 + co0 + j) * 36 + t] = acc[j];
  }
}

// ---------- squash over groups of 8 (primary caps) ----------
__global__ __launch_bounds__(256) void squash8_k(
    const float* __restrict__ p, float* __restrict__ u)
{
  int idx = blockIdx.x * 256 + threadIdx.x;        // (b,i) over 128*1152
  if (idx >= 128 * 1152) return;
  const float4* pp = (const float4*)(p + (size_t)idx * 8);
  float4 a = pp[0], b = pp[1];
  float n2 = a.x * a.x + a.y * a.y + a.z * a.z + a.w * a.w +
             b.x * b.x + b.y * b.y + b.z * b.z + b.w * b.w;
  float sc = (n2 / (1.f + n2)) * rsqrtf(n2 + 1e-8f);
  a.x *= sc; a.y *= sc; a.z *= sc; a.w *= sc;
  b.x *= sc; b.y *= sc; b.z *= sc; b.w *= sc;
  float4* up = (float4*)(u + (size_t)idx * 8);
  up[0] = a; up[1] = b;
}

// ---------- squash over 16 (routing output) ----------
__global__ __launch_bounds__(256) void caps_squash16(
    const float* __restrict__ s, float* __restrict__ v)
{
  int idx = blockIdx.x * 256 + threadIdx.x;        // (b,o) over 128*100
  if (idx >= 12800) return;
  const float4* sp = (const float4*)(s + (size_t)idx * 16);
  float4 a = sp[0], b = sp[1], c = sp[2], d = sp[3];
  float n2 = a.x * a.x + a.y * a.y + a.z * a.z + a.w * a.w +
             b.x * b.x + b.y * b.y + b.z * b.z + b.w * b.w +
             c.x * c.x + c.y * c.y + c.z * c.z + c.w * c.w +
             d.x * d.x + d.y * d.y + d.z * d.z + d.w * d.w;
  float sc = (n2 / (1.f + n2)) * rsqrtf(n2 + 1e-8f);
  a.x *= sc; a.y *= sc; a.z *= sc; a.w *= sc;
  b.x *= sc; b.y *= sc; b.z *= sc; b.w *= sc;
  c.x *= sc; c.y *= sc; c.z *= sc; c.w *= sc;
  d.x *= sc; d.y *= sc; d.z *= sc; d.w *= sc;
  float4* vp = (float4*)(v + (size_t)idx * 16);
  vp[0] = a; vp[1] = b; vp[2] = c; vp[3] = d;
}

// ---------- routing s-pass: s[b,o,d] += sum_{i in chunk,e} c[b,o,i] W[o,i,d,e] u[b,i,e]
// block = 1 wave; (o, 64-i chunk) per block; W chunk (32KB) in LDS; 4 b's/thread.
__global__ __launch_bounds__(64) void caps_spass(
    const float* __restrict__ W, const float* __restrict__ u,
    const float* __restrict__ c, float* __restrict__ s, int uniform)
{
  __shared__ __align__(16) float Wl[8192];
  int o = blockIdx.x, ic = blockIdx.y, t = threadIdx.x;
  const float4* Wg = (const float4*)(W + ((size_t)o * 1152 + (size_t)ic * 64) * 128);
  float4* Wl4 = (float4*)Wl;
  for (int l = t; l < 2048; l += 64) Wl4[l] = Wg[l];
  __syncthreads();
  int dh = t >> 5;          // d half: d = dh*8 + d8
  int bg = t & 31;          // b group: b = bg*4 + r
  float acc[4][8];
  #pragma unroll
  for (int r = 0; r < 4; ++r)
    #pragma unroll
    for (int d = 0; d < 8; ++d) acc[r][d] = 0.f;
  for (int ii = 0; ii < 64; ++ii) {
    int gi = ic * 64 + ii;
    float cu[4][8];
    #pragma unroll
    for (int r = 0; r < 4; ++r) {
      int b = bg * 4 + r;
      float cv = uniform ? 0.01f : c[((size_t)b * 100 + o) * 1152 + gi];
      const float4* up = (const float4*)(u + ((size_t)b * 1152 + gi) * 8);
      float4 u0 = up[0], u1 = up[1];
      cu[r][0] = cv * u0.x; cu[r][1] = cv * u0.y; cu[r][2] = cv * u0.z; cu[r][3] = cv * u0.w;
      cu[r][4] = cv * u1.x; cu[r][5] = cv * u1.y; cu[r][6] = cv * u1.z; cu[r][7] = cv * u1.w;
    }
    const float4* Wr = (const float4*)(Wl + ii * 128 + dh * 64);
    #pragma unroll
    for (int d = 0; d < 8; ++d) {
      float4 wa = Wr[d * 2], wb = Wr[d * 2 + 1];
      #pragma unroll
      for (int r = 0; r < 4; ++r) {
        acc[r][d] += wa.x * cu[r][0] + wa.y * cu[r][1] + wa.z * cu[r][2] + wa.w * cu[r][3]
                   + wb.x * cu[r][4] + wb.y * cu[r][5] + wb.z * cu[r][6] + wb.w * cu[r][7];
      }
    }
  }
  #pragma unroll
  for (int r = 0; r < 4; ++r)
    #pragma unroll
    for (int d = 0; d < 8; ++d)
      atomicAdd(s + ((size_t)(bg * 4 + r) * 100 + o) * 16 + dh * 8 + d, acc[r][d]);
}

// ---------- routing b-update: blog[b,o,i] += sum_d x_hat[b,o,i,d] v[b,o,d]
// thread = one i; W[o,i] (128 f) held in VGPRs across the 128-b loop.
__global__ __launch_bounds__(64) void caps_bupdate(
    const float* __restrict__ W, const float* __restrict__ u,
    const float* __restrict__ v, float* __restrict__ blog)
{
  int o = blockIdx.x, ic = blockIdx.y, t = threadIdx.x;
  int gi = ic * 64 + t;
  const float4* Wg = (const float4*)(W + ((size_t)o * 1152 + gi) * 128);
  float4 w[32];
  #pragma unroll
  for (int l = 0; l < 32; ++l) w[l] = Wg[l];
  for (int b = 0; b < 128; ++b) {
    const float* vp = v + ((size_t)b * 100 + o) * 16;  // uniform -> s_load
    float te[8] = {0, 0, 0, 0, 0, 0, 0, 0};
    #pragma unroll
    for (int d = 0; d < 16; ++d) {
      float vv = vp[d];
      float4 wa = w[d * 2], wb = w[d * 2 + 1];
      te[0] += wa.x * vv; te[1] += wa.y * vv; te[2] += wa.z * vv; te[3] += wa.w * vv;
      te[4] += wb.x * vv; te[5] += wb.y * vv; te[6] += wb.z * vv; te[7] += wb.w * vv;
    }
    const float4* up = (const float4*)(u + ((size_t)b * 1152 + gi) * 8);
    float4 u0 = up[0], u1 = up[1];
    float dot = te[0] * u0.x + te[1] * u0.y + te[2] * u0.z + te[3] * u0.w
              + te[4] * u1.x + te[5] * u1.y + te[6] * u1.z + te[7] * u1.w;
    blog[((size_t)b * 100 + o) * 1152 + gi] += dot;
  }
}

// ---------- softmax over o (=100) per (b,i) ----------
__global__ __launch_bounds__(256) void caps_softmax(
    const float* __restrict__ blog, float* __restrict__ c)
{
  int idx = blockIdx.x * 256 + threadIdx.x;        // (b,i) over 128*1152
  if (idx >= 128 * 1152) return;
  int b = idx / 1152, i = idx % 1152;
  const float* bp = blog + (size_t)b * 115200 + i;
  float m = -3.4e38f;
  for (int o = 0; o < 100; ++o) m = fmaxf(m, bp[(size_t)o * 1152]);
  float sum = 0.f;
  for (int o = 0; o < 100; ++o) sum += __expf(bp[(size_t)o * 1152] - m);
  float inv = 1.f / sum;
  float* cp = c + (size_t)b * 115200 + i;
  for (int o = 0; o < 100; ++o) cp[(size_t)o * 1152] = __expf(bp[(size_t)o * 1152] - m) * inv;
}

// ---------- FC GEMM: C[M,N] = relu?(A[M,K] @ W[K,N] + bias), BM=BN=64 BK=16 TM=TN=4 ----------
__global__ __launch_bounds__(256) void fc_gemm(
    const float* __restrict__ A, const float* __restrict__ W,
    const float* __restrict__ bias, float* __restrict__ C,
    int K, int N, int relu)
{
  __shared__ __align__(16) float As[16][68];       // A^T tile, padded
  __shared__ __align__(16) float Ws[16][64];
  int n0 = blockIdx.x * 64, m0 = blockIdx.y * 64;
  int t = threadIdx.x;
  int tc = t & 15, tr = t >> 4;
  float acc[4][4] = {};
  for (int k0 = 0; k0 < K; k0 += 16) {
    #pragma unroll
    for (int l = t; l < 1024; l += 256) {
      int kk = l & 15, mm = l >> 4;
      As[kk][mm] = A[(size_t)(m0 + mm) * K + k0 + kk];
    }
    #pragma unroll
    for (int l = t; l < 1024; l += 256) {
      int nn = l & 63, kk = l >> 6;
      Ws[kk][nn] = W[(size_t)(k0 + kk) * N + n0 + nn];
    }
    __syncthreads();
    #pragma unroll
    for (int kk = 0; kk < 16; ++kk) {
      float4 a4 = *(const float4*)&As[kk][tr * 4];
      float4 w4 = *(const float4*)&Ws[kk][tc * 4];
      acc[0][0] += a4.x * w4.x; acc[0][1] += a4.x * w4.y; acc[0][2] += a4.x * w4.z; acc[0][3] += a4.x * w4.w;
      acc[1][0] += a4.y * w4.x; acc[1][1] += a4.y * w4.y; acc[1][2] += a4.y * w4.z; acc[1][3] += a4.y * w4.w;
      acc[2][0] += a4.z * w4.x; acc[2][1] += a4.z * w4.y; acc[2][2] += a4.z * w4.z; acc[2][3] += a4.z * w4.w;
      acc[3][0] += a4.w * w4.x; acc[3][1] += a4.w * w4.y; acc[3][2] += a4.w * w4.z; acc[3][3] += a4.w * w4.w;
    }
    __syncthreads();
  }
  #pragma unroll
  for (int r = 0; r < 4; ++r) {
    int m = m0 + tr * 4 + r;
    #pragma unroll
    for (int cl = 0; cl < 4; ++cl) {
      int n = n0 + tc * 4 + cl;
      float vv = acc[r][cl] + bias[n];
      if (relu) vv = fmaxf(vv, 0.f);
      C[(size_t)m * N + n] = vv;
    }
  }
}

// ---------- fc3: [128,4096] @ [4096,100] + bias ----------
__global__ __launch_bounds__(128) void fc3_k(
    const float* __restrict__ A, const float* __restrict__ W,
    const float* __restrict__ bias, float* __restrict__ out)
{
  int m = blockIdx.x, n = threadIdx.x;
  if (n >= 100) return;
  const float* a = A + (size_t)m * 4096;           // uniform -> s_load
  float acc = bias[n];
  for (int k = 0; k < 4096; k += 4) {
    acc += a[k]     * W[(size_t)k * 100 + n]
         + a[k + 1] * W[(size_t)(k + 1) * 100 + n]
         + a[k + 2] * W[(size_t)(k + 2) * 100 + n]
         + a[k + 3] * W[(size_t)(k + 3) * 100 + n];
  }
  out[(size_t)m * 100 + n] = acc;
}

// ============================================================================
extern "C" void kernel_launch(void* const* d_in, const int* in_sizes, int n_in,
                              void* d_out, int out_size, void* d_ws, size_t ws_size,
                              hipStream_t stream)
{
  (void)in_sizes; (void)n_in; (void)out_size; (void)ws_size;
  const float* x   = (const float*)d_in[0];
  const float* cw1 = (const float*)d_in[1];
  const float* cb1 = (const float*)d_in[2];
  const float* cw2 = (const float*)d_in[3];
  const float* cb2 = (const float*)d_in[4];
  const float* cw3 = (const float*)d_in[5];
  const float* cb3 = (const float*)d_in[6];
  const float* pw  = (const float*)d_in[7];
  const float* pb  = (const float*)d_in[8];
  const float* Wc  = (const float*)d_in[9];
  const float* fw1 = (const float*)d_in[10];
  const float* fb1 = (const float*)d_in[11];
  const float* fw2 = (const float*)d_in[12];
  const float* fb2 = (const float*)d_in[13];
  const float* fw3 = (const float*)d_in[14];
  const float* fb3 = (const float*)d_in[15];
  float* ws = (float*)d_ws;

  // Workspace arena (floats). h-buffer region [0, 15.73M) is reused as blog
  // (14.75M) once pcaps has consumed h3. Total: 34,291,712 floats = 137.2 MB.
  const size_t OFF_A  = 0;          // 12,582,912 : h1 / h2 / h3 ; later blog
  const size_t OFF_B  = 12582912;   //  3,145,728 : h1p / h2p
  const size_t OFF_U  = 15728640;   //  1,179,648 : u [128,1152,8]
  const size_t OFF_P  = 16908288;   //  1,179,648 : p [128,256,36]
  const size_t OFF_C  = 18087936;   // 14,745,600 : c [128,100,1152]
  const size_t OFF_V  = 32833536;   //    204,800 : v [128,100,16]
  const size_t OFF_S  = 33038336;   //    204,800 : s [128,100,16]
  const size_t OFF_F1 = 33243136;   //    524,288 : f1 [128,4096]
  const size_t OFF_F2 = 33767424;   //    524,288 : f2 [128,4096]

  float* A    = ws + OFF_A;
  float* Bf   = ws + OFF_B;
  float* u    = ws + OFF_U;
  float* p    = ws + OFF_P;
  float* c    = ws + OFF_C;
  float* v    = ws + OFF_V;
  float* s    = ws + OFF_S;
  float* f1   = ws + OFF_F1;
  float* f2   = ws + OFF_F2;
  float* blog = ws + OFF_A;

  // Backbone
  conv1_k<<<49152, 256, 0, stream>>>(x, cw1, cb1, A);                 // [128,96,32,32]
  maxpool_k<<<12288, 256, 0, stream>>>(A, Bf, 32);                    // [128,96,16,16]
  convk<96, 16, 8><<<dim3(32, 128), 256, 0, stream>>>(Bf, cw2, cb2, A, 256);   // [128,256,16,16]
  maxpool_k<<<8192, 256, 0, stream>>>(A, Bf, 16);                     // [128,256,8,8]
  convk<256, 8, 16><<<dim3(24, 128), 64, 0, stream>>>(Bf, cw3, cb3, A, 384);   // [128,384,8,8]
  pcaps_k<<<dim3(16, 128), 64, 0, stream>>>(A, pw, pb, p);            // [128,256,36]
  squash8_k<<<576, 256, 0, stream>>>(p, u);                           // [128,1152,8]

  // Dynamic routing (3 iterations), x_hat recomputed on the fly
  hipMemsetAsync(blog, 0, (size_t)14745600 * 4, stream);
  for (int r = 0; r < 3; ++r) {
    hipMemsetAsync(s, 0, (size_t)204800 * 4, stream);
    if (r == 0) {
      caps_spass<<<dim3(100, 18), 64, 0, stream>>>(Wc, u, u /*dummy*/, s, 1);
    } else {
      caps_softmax<<<576, 256, 0, stream>>>(blog, c);
      caps_spass<<<dim3(100, 18), 64, 0, stream>>>(Wc, u, c, s, 0);
    }
    caps_squash16<<<50, 256, 0, stream>>>(s, v);
    if (r < 2)
      caps_bupdate<<<dim3(100, 18), 64, 0, stream>>>(Wc, u, v, blog);
  }

  // FC head; v is already [128,1600] flat
  fc_gemm<<<dim3(64, 2), 256, 0, stream>>>(v,  fw1, fb1, f1, 1600, 4096, 1);
  fc_gemm<<<dim3(64, 2), 256, 0, stream>>>(f1, fw2, fb2, f2, 4096, 4096, 1);
  fc3_k<<<128, 128, 0, stream>>>(f2, fw3, fb3, (float*)d_out);
}

// Round 2
// 3792.155 us; speedup vs baseline: 1.0652x; 1.0652x over previous
//
#include <hip/hip_runtime.h>
#include <cstddef>

// ============================================================================
// AlexCapsNet CIFAR-100 forward, fp32. Round 1: conv2/conv3/pcaps rewritten as
// im2col-on-the-fly GEMM (weights are [CO, CI*9] contiguous in OIHW layout).
// ============================================================================

// ---------- conv1: direct 3->96 k3 s1 p1 + relu ----------
__global__ __launch_bounds__(256) void conv1_k(
    const float* __restrict__ x, const float* __restrict__ wt,
    const float* __restrict__ bias, float* __restrict__ out)
{
  int idx = blockIdx.x * 256 + threadIdx.x;          // [b,co,h,w] over 128*96*32*32
  int w = idx & 31, h = (idx >> 5) & 31;
  int t2 = idx >> 10;
  int co = t2 % 96, b = t2 / 96;
  float acc = bias[co];
  #pragma unroll
  for (int ci = 0; ci < 3; ++ci) {
    const float* xp = x + ((size_t)(b * 3 + ci) << 10);
    const float* wp = wt + (size_t)(co * 3 + ci) * 9;
    #pragma unroll
    for (int dh = 0; dh < 3; ++dh) {
      int ih = h + dh - 1;
      if (ih < 0 || ih > 31) continue;
      #pragma unroll
      for (int dw = 0; dw < 3; ++dw) {
        int iw = w + dw - 1;
        if (iw < 0 || iw > 31) continue;
        acc += xp[(ih << 5) + iw] * wp[dh * 3 + dw];
      }
    }
  }
  out[idx] = fmaxf(acc, 0.f);
}

// ---------- maxpool k3 s2 p1 (torch semantics) ----------
__global__ __launch_bounds__(256) void maxpool_k(
    const float* __restrict__ in, float* __restrict__ out, int H)
{
  int Ho = H >> 1;
  int idx = blockIdx.x * 256 + threadIdx.x;          // [bc, ho, wo]
  int wo = idx % Ho;
  int t2 = idx / Ho;
  int ho = t2 % Ho;
  int bc = t2 / Ho;
  const float* ip = in + (size_t)bc * H * H;
  float m = -3.4e38f;
  #pragma unroll
  for (int dh = 0; dh < 3; ++dh) {
    int ih = 2 * ho - 1 + dh;
    if (ih < 0 || ih >= H) continue;
    #pragma unroll
    for (int dw = 0; dw < 3; ++dw) {
      int iw = 2 * wo - 1 + dw;
      if (iw < 0 || iw >= H) continue;
      m = fmaxf(m, ip[ih * H + iw]);
    }
  }
  out[idx] = m;
}

// ---------- conv as GEMM with on-the-fly im2col ----------
// C[m=co][n=b*NPIX+xy] = sum_k W[co][k] * X[k][n],  k = ci*9 + dh*3 + dw.
// Weights [CO, CI*9] are exactly the OIHW tensor flat. BM=BN=64, BK=16,
// 256 threads, 4x4 register blocking. out layout: [B, CO, NPIX] (+opt relu).
template <int CI, int H, int PAD, int WO>
__global__ __launch_bounds__(256) void convgemm_k(
    const float* __restrict__ in, const float* __restrict__ wt,
    const float* __restrict__ bias, float* __restrict__ out,
    int CO, int relu)
{
  constexpr int K = CI * 9;
  constexpr int NPIX = WO * WO;
  __shared__ __align__(16) float As[16][68];   // weights^T tile, padded
  __shared__ __align__(16) float Bs[16][64];   // im2col tile
  int n0 = blockIdx.x * 64, m0 = blockIdx.y * 64;
  int t = threadIdx.x;
  int tc = t & 15, tr = t >> 4;
  float acc[4][4] = {};
  for (int k0 = 0; k0 < K; k0 += 16) {
    #pragma unroll
    for (int l = t; l < 1024; l += 256) {
      int kk = l & 15, mm = l >> 4;
      As[kk][mm] = wt[(size_t)(m0 + mm) * K + k0 + kk];
    }
    #pragma unroll
    for (int l = t; l < 1024; l += 256) {
      int nn = l & 63, kk = l >> 6;
      int k = k0 + kk;
      int ci = k / 9, r = k - ci * 9;
      int dh = r / 3, dw = r - dh * 3;
      int n = n0 + nn;
      int b = n / NPIX, xy = n - b * NPIX;
      int ho = xy / WO, wo = xy - ho * WO;
      int ih = ho + dh - PAD, iw = wo + dw - PAD;
      float v = 0.f;
      if (ih >= 0 && ih < H && iw >= 0 && iw < H)
        v = in[((size_t)(b * CI + ci) * H + ih) * H + iw];
      Bs[kk][nn] = v;
    }
    __syncthreads();
    #pragma unroll
    for (int kk = 0; kk < 16; ++kk) {
      float4 a4 = *(const float4*)&As[kk][tr * 4];
      float4 w4 = *(const float4*)&Bs[kk][tc * 4];
      acc[0][0] += a4.x * w4.x; acc[0][1] += a4.x * w4.y; acc[0][2] += a4.x * w4.z; acc[0][3] += a4.x * w4.w;
      acc[1][0] += a4.y * w4.x; acc[1][1] += a4.y * w4.y; acc[1][2] += a4.y * w4.z; acc[1][3] += a4.y * w4.w;
      acc[2][0] += a4.z * w4.x; acc[2][1] += a4.z * w4.y; acc[2][2] += a4.z * w4.z; acc[2][3] += a4.z * w4.w;
      acc[3][0] += a4.w * w4.x; acc[3][1] += a4.w * w4.y; acc[3][2] += a4.w * w4.z; acc[3][3] += a4.w * w4.w;
    }
    __syncthreads();
  }
  #pragma unroll
  for (int r = 0; r < 4; ++r) {
    int m = m0 + tr * 4 + r;
    float bv = bias[m];
    #pragma unroll
    for (int cl = 0; cl < 4; ++cl) {
      int n = n0 + tc * 4 + cl;
      int b = n / NPIX, xy = n - b * NPIX;
      float vv = acc[r][cl] + bv;
      if (relu) vv = fmaxf(vv, 0.f);
      out[((size_t)b * CO + m) * NPIX + xy] = vv;
    }
  }
}

// ---------- squash over groups of 8 (primary caps) ----------
__global__ __launch_bounds__(256) void squash8_k(
    const float* __restrict__ p, float* __restrict__ u)
{
  int idx = blockIdx.x * 256 + threadIdx.x;        // (b,i) over 128*1152
  if (idx >= 128 * 1152) return;
  const float4* pp = (const float4*)(p + (size_t)idx * 8);
  float4 a = pp[0], b = pp[1];
  float n2 = a.x * a.x + a.y * a.y + a.z * a.z + a.w * a.w +
             b.x * b.x + b.y * b.y + b.z * b.z + b.w * b.w;
  float sc = (n2 / (1.f + n2)) * rsqrtf(n2 + 1e-8f);
  a.x *= sc; a.y *= sc; a.z *= sc; a.w *= sc;
  b.x *= sc; b.y *= sc; b.z *= sc; b.w *= sc;
  float4* up = (float4*)(u + (size_t)idx * 8);
  up[0] = a; up[1] = b;
}

// ---------- squash over 16 (routing output) ----------
__global__ __launch_bounds__(256) void caps_squash16(
    const float* __restrict__ s, float* __restrict__ v)
{
  int idx = blockIdx.x * 256 + threadIdx.x;        // (b,o) over 128*100
  if (idx >= 12800) return;
  const float4* sp = (const float4*)(s + (size_t)idx * 16);
  float4 a = sp[0], b = sp[1], c = sp[2], d = sp[3];
  float n2 = a.x * a.x + a.y * a.y + a.z * a.z + a.w * a.w +
             b.x * b.x + b.y * b.y + b.z * b.z + b.w * b.w +
             c.x * c.x + c.y * c.y + c.z * c.z + c.w * c.w +
             d.x * d.x + d.y * d.y + d.z * d.z + d.w * d.w;
  float sc = (n2 / (1.f + n2)) * rsqrtf(n2 + 1e-8f);
  a.x *= sc; a.y *= sc; a.z *= sc; a.w *= sc;
  b.x *= sc; b.y *= sc; b.z *= sc; b.w *= sc;
  c.x *= sc; c.y *= sc; c.z *= sc; c.w *= sc;
  d.x *= sc; d.y *= sc; d.z *= sc; d.w *= sc;
  float4* vp = (float4*)(v + (size_t)idx * 16);
  vp[0] = a; vp[1] = b; vp[2] = c; vp[3] = d;
}

// ---------- routing s-pass: s[b,o,d] += sum_{i in chunk,e} c[b,o,i] W[o,i,d,e] u[b,i,e]
__global__ __launch_bounds__(64) void caps_spass(
    const float* __restrict__ W, const float* __restrict__ u,
    const float* __restrict__ c, float* __restrict__ s, int uniform)
{
  __shared__ __align__(16) float Wl[8192];
  int o = blockIdx.x, ic = blockIdx.y, t = threadIdx.x;
  const float4* Wg = (const float4*)(W + ((size_t)o * 1152 + (size_t)ic * 64) * 128);
  float4* Wl4 = (float4*)Wl;
  for (int l = t; l < 2048; l += 64) Wl4[l] = Wg[l];
  __syncthreads();
  int dh = t >> 5;          // d half: d = dh*8 + d8
  int bg = t & 31;          // b group: b = bg*4 + r
  float acc[4][8];
  #pragma unroll
  for (int r = 0; r < 4; ++r)
    #pragma unroll
    for (int d = 0; d < 8; ++d) acc[r][d] = 0.f;
  for (int ii = 0; ii < 64; ++ii) {
    int gi = ic * 64 + ii;
    float cu[4][8];
    #pragma unroll
    for (int r = 0; r < 4; ++r) {
      int b = bg * 4 + r;
      float cv = uniform ? 0.01f : c[((size_t)b * 100 + o) * 1152 + gi];
      const float4* up = (const float4*)(u + ((size_t)b * 1152 + gi) * 8);
      float4 u0 = up[0], u1 = up[1];
      cu[r][0] = cv * u0.x; cu[r][1] = cv * u0.y; cu[r][2] = cv * u0.z; cu[r][3] = cv * u0.w;
      cu[r][4] = cv * u1.x; cu[r][5] = cv * u1.y; cu[r][6] = cv * u1.z; cu[r][7] = cv * u1.w;
    }
    const float4* Wr = (const float4*)(Wl + ii * 128 + dh * 64);
    #pragma unroll
    for (int d = 0; d < 8; ++d) {
      float4 wa = Wr[d * 2], wb = Wr[d * 2 + 1];
      #pragma unroll
      for (int r = 0; r < 4; ++r) {
        acc[r][d] += wa.x * cu[r][0] + wa.y * cu[r][1] + wa.z * cu[r][2] + wa.w * cu[r][3]
                   + wb.x * cu[r][4] + wb.y * cu[r][5] + wb.z * cu[r][6] + wb.w * cu[r][7];
      }
    }
  }
  #pragma unroll
  for (int r = 0; r < 4; ++r)
    #pragma unroll
    for (int d = 0; d < 8; ++d)
      atomicAdd(s + ((size_t)(bg * 4 + r) * 100 + o) * 16 + dh * 8 + d, acc[r][d]);
}

// ---------- routing b-update: blog[b,o,i] += sum_d x_hat[b,o,i,d] v[b,o,d]
__global__ __launch_bounds__(64) void caps_bupdate(
    const float* __restrict__ W, const float* __restrict__ u,
    const float* __restrict__ v, float* __restrict__ blog)
{
  int o = blockIdx.x, ic = blockIdx.y, t = threadIdx.x;
  int gi = ic * 64 + t;
  const float4* Wg = (const float4*)(W + ((size_t)o * 1152 + gi) * 128);
  float4 w[32];
  #pragma unroll
  for (int l = 0; l < 32; ++l) w[l] = Wg[l];
  for (int b = 0; b < 128; ++b) {
    const float* vp = v + ((size_t)b * 100 + o) * 16;  // uniform -> s_load
    float te[8] = {0, 0, 0, 0, 0, 0, 0, 0};
    #pragma unroll
    for (int d = 0; d < 16; ++d) {
      float vv = vp[d];
      float4 wa = w[d * 2], wb = w[d * 2 + 1];
      te[0] += wa.x * vv; te[1] += wa.y * vv; te[2] += wa.z * vv; te[3] += wa.w * vv;
      te[4] += wb.x * vv; te[5] += wb.y * vv; te[6] += wb.z * vv; te[7] += wb.w * vv;
    }
    const float4* up = (const float4*)(u + ((size_t)b * 1152 + gi) * 8);
    float4 u0 = up[0], u1 = up[1];
    float dot = te[0] * u0.x + te[1] * u0.y + te[2] * u0.z + te[3] * u0.w
              + te[4] * u1.x + te[5] * u1.y + te[6] * u1.z + te[7] * u1.w;
    blog[((size_t)b * 100 + o) * 1152 + gi] += dot;
  }
}

// ---------- softmax over o (=100) per (b,i) ----------
__global__ __launch_bounds__(256) void caps_softmax(
    const float* __restrict__ blog, float* __restrict__ c)
{
  int idx = blockIdx.x * 256 + threadIdx.x;        // (b,i) over 128*1152
  if (idx >= 128 * 1152) return;
  int b = idx / 1152, i = idx % 1152;
  const float* bp = blog + (size_t)b * 115200 + i;
  float m = -3.4e38f;
  for (int o = 0; o < 100; ++o) m = fmaxf(m, bp[(size_t)o * 1152]);
  float sum = 0.f;
  for (int o = 0; o < 100; ++o) sum += __expf(bp[(size_t)o * 1152] - m);
  float inv = 1.f / sum;
  float* cp = c + (size_t)b * 115200 + i;
  for (int o = 0; o < 100; ++o) cp[(size_t)o * 1152] = __expf(bp[(size_t)o * 1152] - m) * inv;
}

// ---------- FC GEMM: C[M,N] = relu?(A[M,K] @ W[K,N] + bias) ----------
__global__ __launch_bounds__(256) void fc_gemm(
    const float* __restrict__ A, const float* __restrict__ W,
    const float* __restrict__ bias, float* __restrict__ C,
    int K, int N, int relu)
{
  __shared__ __align__(16) float As[16][68];       // A^T tile, padded
  __shared__ __align__(16) float Ws[16][64];
  int n0 = blockIdx.x * 64, m0 = blockIdx.y * 64;
  int t = threadIdx.x;
  int tc = t & 15, tr = t >> 4;
  float acc[4][4] = {};
  for (int k0 = 0; k0 < K; k0 += 16) {
    #pragma unroll
    for (int l = t; l < 1024; l += 256) {
      int kk = l & 15, mm = l >> 4;
      As[kk][mm] = A[(size_t)(m0 + mm) * K + k0 + kk];
    }
    #pragma unroll
    for (int l = t; l < 1024; l += 256) {
      int nn = l & 63, kk = l >> 6;
      Ws[kk][nn] = W[(size_t)(k0 + kk) * N + n0 + nn];
    }
    __syncthreads();
    #pragma unroll
    for (int kk = 0; kk < 16; ++kk) {
      float4 a4 = *(const float4*)&As[kk][tr * 4];
      float4 w4 = *(const float4*)&Ws[kk][tc * 4];
      acc[0][0] += a4.x * w4.x; acc[0][1] += a4.x * w4.y; acc[0][2] += a4.x * w4.z; acc[0][3] += a4.x * w4.w;
      acc[1][0] += a4.y * w4.x; acc[1][1] += a4.y * w4.y; acc[1][2] += a4.y * w4.z; acc[1][3] += a4.y * w4.w;
      acc[2][0] += a4.z * w4.x; acc[2][1] += a4.z * w4.y; acc[2][2] += a4.z * w4.z; acc[2][3] += a4.z * w4.w;
      acc[3][0] += a4.w * w4.x; acc[3][1] += a4.w * w4.y; acc[3][2] += a4.w * w4.z; acc[3][3] += a4.w * w4.w;
    }
    __syncthreads();
  }
  #pragma unroll
  for (int r = 0; r < 4; ++r) {
    int m = m0 + tr * 4 + r;
    #pragma unroll
    for (int cl = 0; cl < 4; ++cl) {
      int n = n0 + tc * 4 + cl;
      float vv = acc[r][cl] + bias[n];
      if (relu) vv = fmaxf(vv, 0.f);
      C[(size_t)m * N + n] = vv;
    }
  }
}

// ---------- fc3: [128,4096] @ [4096,100] + bias ----------
__global__ __launch_bounds__(128) void fc3_k(
    const float* __restrict__ A, const float* __restrict__ W,
    const float* __restrict__ bias, float* __restrict__ out)
{
  int m = blockIdx.x, n = threadIdx.x;
  if (n >= 100) return;
  const float* a = A + (size_t)m * 4096;           // uniform -> s_load
  float acc = bias[n];
  for (int k = 0; k < 4096; k += 4) {
    acc += a[k]     * W[(size_t)k * 100 + n]
         + a[k + 1] * W[(size_t)(k + 1) * 100 + n]
         + a[k + 2] * W[(size_t)(k + 2) * 100 + n]
         + a[k + 3] * W[(size_t)(k + 3) * 100 + n];
  }
  out[(size_t)m * 100 + n] = acc;
}

// ============================================================================
extern "C" void kernel_launch(void* const* d_in, const int* in_sizes, int n_in,
                              void* d_out, int out_size, void* d_ws, size_t ws_size,
                              hipStream_t stream)
{
  (void)in_sizes; (void)n_in; (void)out_size; (void)ws_size;
  const float* x   = (const float*)d_in[0];
  const float* cw1 = (const float*)d_in[1];
  const float* cb1 = (const float*)d_in[2];
  const float* cw2 = (const float*)d_in[3];
  const float* cb2 = (const float*)d_in[4];
  const float* cw3 = (const float*)d_in[5];
  const float* cb3 = (const float*)d_in[6];
  const float* pw  = (const float*)d_in[7];
  const float* pb  = (const float*)d_in[8];
  const float* Wc  = (const float*)d_in[9];
  const float* fw1 = (const float*)d_in[10];
  const float* fb1 = (const float*)d_in[11];
  const float* fw2 = (const float*)d_in[12];
  const float* fb2 = (const float*)d_in[13];
  const float* fw3 = (const float*)d_in[14];
  const float* fb3 = (const float*)d_in[15];
  float* ws = (float*)d_ws;

  // Workspace arena (floats). h-buffer region reused as blog after pcaps.
  const size_t OFF_A  = 0;          // 12,582,912 : h1 / h2 / h3 ; later blog
  const size_t OFF_B  = 12582912;   //  3,145,728 : h1p / h2p
  const size_t OFF_U  = 15728640;   //  1,179,648 : u [128,1152,8]
  const size_t OFF_P  = 16908288;   //  1,179,648 : p [128,256,36]
  const size_t OFF_C  = 18087936;   // 14,745,600 : c [128,100,1152]
  const size_t OFF_V  = 32833536;   //    204,800 : v [128,100,16]
  const size_t OFF_S  = 33038336;   //    204,800 : s [128,100,16]
  const size_t OFF_F1 = 33243136;   //    524,288 : f1 [128,4096]
  const size_t OFF_F2 = 33767424;   //    524,288 : f2 [128,4096]

  float* A    = ws + OFF_A;
  float* Bf   = ws + OFF_B;
  float* u    = ws + OFF_U;
  float* p    = ws + OFF_P;
  float* c    = ws + OFF_C;
  float* v    = ws + OFF_V;
  float* s    = ws + OFF_S;
  float* f1   = ws + OFF_F1;
  float* f2   = ws + OFF_F2;
  float* blog = ws + OFF_A;

  // Backbone
  conv1_k<<<49152, 256, 0, stream>>>(x, cw1, cb1, A);                 // [128,96,32,32]
  maxpool_k<<<12288, 256, 0, stream>>>(A, Bf, 32);                    // [128,96,16,16]
  // conv2: CI=96 H=16 pad=1 -> N=128*256=32768, K=864, CO=256
  convgemm_k<96, 16, 1, 16><<<dim3(512, 4), 256, 0, stream>>>(Bf, cw2, cb2, A, 256, 1);
  maxpool_k<<<8192, 256, 0, stream>>>(A, Bf, 16);                     // [128,256,8,8]
  // conv3: CI=256 H=8 pad=1 -> N=128*64=8192, K=2304, CO=384
  convgemm_k<256, 8, 1, 8><<<dim3(128, 6), 256, 0, stream>>>(Bf, cw3, cb3, A, 384, 1);
  // pcaps: CI=384 H=8 pad=0 -> N=128*36=4608, K=3456, CO=256, no relu
  convgemm_k<384, 8, 0, 6><<<dim3(72, 4), 256, 0, stream>>>(A, pw, pb, p, 256, 0);
  squash8_k<<<576, 256, 0, stream>>>(p, u);                           // [128,1152,8]

  // Dynamic routing (3 iterations), x_hat recomputed on the fly
  hipMemsetAsync(blog, 0, (size_t)14745600 * 4, stream);
  for (int r = 0; r < 3; ++r) {
    hipMemsetAsync(s, 0, (size_t)204800 * 4, stream);
    if (r == 0) {
      caps_spass<<<dim3(100, 18), 64, 0, stream>>>(Wc, u, u /*dummy*/, s, 1);
    } else {
      caps_softmax<<<576, 256, 0, stream>>>(blog, c);
      caps_spass<<<dim3(100, 18), 64, 0, stream>>>(Wc, u, c, s, 0);
    }
    caps_squash16<<<50, 256, 0, stream>>>(s, v);
    if (r < 2)
      caps_bupdate<<<dim3(100, 18), 64, 0, stream>>>(Wc, u, v, blog);
  }

  // FC head; v is already [128,1600] flat
  fc_gemm<<<dim3(64, 2), 256, 0, stream>>>(v,  fw1, fb1, f1, 1600, 4096, 1);
  fc_gemm<<<dim3(64, 2), 256, 0, stream>>>(f1, fw2, fb2, f2, 4096, 4096, 1);
  fc3_k<<<128, 128, 0, stream>>>(f2, fw3, fb3, (float*)d_out);
}

// Round 3
// 2777.710 us; speedup vs baseline: 1.4542x; 1.3652x over previous
//
#include <hip/hip_runtime.h>
#include <cstddef>

// ============================================================================
// AlexCapsNet CIFAR-100 forward, fp32. Round 3: latency-hiding round.
// - split-K + register-prefetch pipeline for all GEMM-shaped kernels
// - 256-thread routing kernels (4 waves/block)
// ============================================================================

// ---------- conv1: direct 3->96 k3 s1 p1 + relu ----------
__global__ __launch_bounds__(256) void conv1_k(
    const float* __restrict__ x, const float* __restrict__ wt,
    const float* __restrict__ bias, float* __restrict__ out)
{
  int idx = blockIdx.x * 256 + threadIdx.x;          // [b,co,h,w] over 128*96*32*32
  int w = idx & 31, h = (idx >> 5) & 31;
  int t2 = idx >> 10;
  int co = t2 % 96, b = t2 / 96;
  float acc = bias[co];
  #pragma unroll
  for (int ci = 0; ci < 3; ++ci) {
    const float* xp = x + ((size_t)(b * 3 + ci) << 10);
    const float* wp = wt + (size_t)(co * 3 + ci) * 9;
    #pragma unroll
    for (int dh = 0; dh < 3; ++dh) {
      int ih = h + dh - 1;
      if (ih < 0 || ih > 31) continue;
      #pragma unroll
      for (int dw = 0; dw < 3; ++dw) {
        int iw = w + dw - 1;
        if (iw < 0 || iw > 31) continue;
        acc += xp[(ih << 5) + iw] * wp[dh * 3 + dw];
      }
    }
  }
  out[idx] = fmaxf(acc, 0.f);
}

// ---------- maxpool k3 s2 p1 ----------
__global__ __launch_bounds__(256) void maxpool_k(
    const float* __restrict__ in, float* __restrict__ out, int H)
{
  int Ho = H >> 1;
  int idx = blockIdx.x * 256 + threadIdx.x;
  int wo = idx % Ho;
  int t2 = idx / Ho;
  int ho = t2 % Ho;
  int bc = t2 / Ho;
  const float* ip = in + (size_t)bc * H * H;
  float m = -3.4e38f;
  #pragma unroll
  for (int dh = 0; dh < 3; ++dh) {
    int ih = 2 * ho - 1 + dh;
    if (ih < 0 || ih >= H) continue;
    #pragma unroll
    for (int dw = 0; dw < 3; ++dw) {
      int iw = 2 * wo - 1 + dw;
      if (iw < 0 || iw >= H) continue;
      m = fmaxf(m, ip[ih * H + iw]);
    }
  }
  out[idx] = m;
}

// ---------- conv as GEMM, on-the-fly im2col, register-prefetch pipeline ----------
// SPLIT: grid.z splits K; partials atomicAdd'ed into pre-zeroed out, bias/relu skipped.
template <int CI, int H, int PAD, int WO, bool SPLIT>
__global__ __launch_bounds__(256) void convgemm_k(
    const float* __restrict__ in, const float* __restrict__ wt,
    const float* __restrict__ bias, float* __restrict__ out,
    int CO, int relu, int KC)
{
  constexpr int K = CI * 9;
  constexpr int NPIX = WO * WO;
  __shared__ __align__(16) float As[16][72];   // weights^T tile (16B-aligned rows)
  __shared__ __align__(16) float Bs[16][64];   // im2col tile
  int n0 = blockIdx.x * 64, m0 = blockIdx.y * 64;
  int kbeg = SPLIT ? blockIdx.z * KC : 0;
  int kend = SPLIT ? kbeg + KC : K;
  int t = threadIdx.x;
  int tc = t & 15, tr = t >> 4;

  auto loadA = [&](int k0, float* r) {
    #pragma unroll
    for (int i = 0; i < 4; ++i) {
      int l = t + i * 256; int kk = l & 15, mm = l >> 4;
      r[i] = wt[(size_t)(m0 + mm) * K + k0 + kk];
    }
  };
  auto loadB = [&](int k0, float* r) {
    #pragma unroll
    for (int i = 0; i < 4; ++i) {
      int l = t + i * 256; int nn = l & 63, kk = l >> 6;
      int k = k0 + kk;
      int ci = k / 9, rr = k - ci * 9;
      int dh = rr / 3, dw = rr - dh * 3;
      int n = n0 + nn;
      int b = n / NPIX, xy = n - b * NPIX;
      int ho = xy / WO, wo = xy - ho * WO;
      int ih = ho + dh - PAD, iw = wo + dw - PAD;
      r[i] = (ih >= 0 && ih < H && iw >= 0 && iw < H)
               ? in[((size_t)(b * CI + ci) * H + ih) * H + iw] : 0.f;
    }
  };

  float pa[4], pb[4];
  loadA(kbeg, pa); loadB(kbeg, pb);
  float acc[4][4] = {};
  for (int k0 = kbeg; k0 < kend; k0 += 16) {
    if (k0 > kbeg) __syncthreads();
    #pragma unroll
    for (int i = 0; i < 4; ++i) { int l = t + i * 256; As[l & 15][l >> 4] = pa[i]; }
    #pragma unroll
    for (int i = 0; i < 4; ++i) { int l = t + i * 256; Bs[l >> 6][l & 63] = pb[i]; }
    __syncthreads();
    if (k0 + 16 < kend) { loadA(k0 + 16, pa); loadB(k0 + 16, pb); }
    #pragma unroll
    for (int kk = 0; kk < 16; ++kk) {
      float4 a4 = *(const float4*)&As[kk][tr * 4];
      float4 w4 = *(const float4*)&Bs[kk][tc * 4];
      acc[0][0] += a4.x * w4.x; acc[0][1] += a4.x * w4.y; acc[0][2] += a4.x * w4.z; acc[0][3] += a4.x * w4.w;
      acc[1][0] += a4.y * w4.x; acc[1][1] += a4.y * w4.y; acc[1][2] += a4.y * w4.z; acc[1][3] += a4.y * w4.w;
      acc[2][0] += a4.z * w4.x; acc[2][1] += a4.z * w4.y; acc[2][2] += a4.z * w4.z; acc[2][3] += a4.z * w4.w;
      acc[3][0] += a4.w * w4.x; acc[3][1] += a4.w * w4.y; acc[3][2] += a4.w * w4.z; acc[3][3] += a4.w * w4.w;
    }
  }
  #pragma unroll
  for (int r = 0; r < 4; ++r) {
    int m = m0 + tr * 4 + r;
    float bv = SPLIT ? 0.f : bias[m];
    #pragma unroll
    for (int cl = 0; cl < 4; ++cl) {
      int n = n0 + tc * 4 + cl;
      int b = n / NPIX, xy = n - b * NPIX;
      size_t oidx = ((size_t)b * CO + m) * NPIX + xy;
      if (SPLIT) {
        atomicAdd(out + oidx, acc[r][cl]);
      } else {
        float vv = acc[r][cl] + bv;
        if (relu) vv = fmaxf(vv, 0.f);
        out[oidx] = vv;
      }
    }
  }
}

// ---------- squash8 (+primary-caps bias add; p holds conv-only partials) ----------
__global__ __launch_bounds__(256) void squash8_k(
    const float* __restrict__ p, const float* __restrict__ pb,
    float* __restrict__ u)
{
  int idx = blockIdx.x * 256 + threadIdx.x;        // (b,i) over 128*1152
  if (idx >= 128 * 1152) return;
  int i = idx % 1152;
  int f0 = i * 8;                                   // within-sample flat index
  const float4* pp = (const float4*)(p + (size_t)idx * 8);
  float4 a = pp[0], b = pp[1];
  float pv[8] = {a.x, a.y, a.z, a.w, b.x, b.y, b.z, b.w};
  #pragma unroll
  for (int e = 0; e < 8; ++e) pv[e] += pb[(f0 + e) / 36];
  float n2 = 1e-30f;
  #pragma unroll
  for (int e = 0; e < 8; ++e) n2 += pv[e] * pv[e];
  n2 -= 1e-30f;
  float sc = (n2 / (1.f + n2)) * rsqrtf(n2 + 1e-8f);
  float4 o0 = {pv[0] * sc, pv[1] * sc, pv[2] * sc, pv[3] * sc};
  float4 o1 = {pv[4] * sc, pv[5] * sc, pv[6] * sc, pv[7] * sc};
  float4* up = (float4*)(u + (size_t)idx * 8);
  up[0] = o0; up[1] = o1;
}

// ---------- squash over 16 (routing output) ----------
__global__ __launch_bounds__(256) void caps_squash16(
    const float* __restrict__ s, float* __restrict__ v)
{
  int idx = blockIdx.x * 256 + threadIdx.x;        // (b,o) over 128*100
  if (idx >= 12800) return;
  const float4* sp = (const float4*)(s + (size_t)idx * 16);
  float4 a = sp[0], b = sp[1], c = sp[2], d = sp[3];
  float n2 = a.x * a.x + a.y * a.y + a.z * a.z + a.w * a.w +
             b.x * b.x + b.y * b.y + b.z * b.z + b.w * b.w +
             c.x * c.x + c.y * c.y + c.z * c.z + c.w * c.w +
             d.x * d.x + d.y * d.y + d.z * d.z + d.w * d.w;
  float sc = (n2 / (1.f + n2)) * rsqrtf(n2 + 1e-8f);
  a.x *= sc; a.y *= sc; a.z *= sc; a.w *= sc;
  b.x *= sc; b.y *= sc; b.z *= sc; b.w *= sc;
  c.x *= sc; c.y *= sc; c.z *= sc; c.w *= sc;
  d.x *= sc; d.y *= sc; d.z *= sc; d.w *= sc;
  float4* vp = (float4*)(v + (size_t)idx * 16);
  vp[0] = a; vp[1] = b; vp[2] = c; vp[3] = d;
}

// ---------- routing s-pass (256 thr): waves split the 64-i chunk, LDS reduce ----------
__global__ __launch_bounds__(256) void caps_spass(
    const float* __restrict__ W, const float* __restrict__ u,
    const float* __restrict__ c, float* __restrict__ s, int uniform)
{
  __shared__ __align__(16) float Wl[8192];
  int o = blockIdx.x, ic = blockIdx.y, t = threadIdx.x;
  const float4* Wg = (const float4*)(W + ((size_t)o * 1152 + (size_t)ic * 64) * 128);
  float4* Wl4 = (float4*)Wl;
  for (int l = t; l < 2048; l += 256) Wl4[l] = Wg[l];
  __syncthreads();
  int wave = t >> 6, lane = t & 63;
  int dh = lane >> 5, bg = lane & 31;
  float acc[4][8] = {};
  #pragma unroll 4
  for (int iw2 = 0; iw2 < 16; ++iw2) {
    int ii = wave * 16 + iw2;
    int gi = ic * 64 + ii;
    float cu[4][8];
    #pragma unroll
    for (int r = 0; r < 4; ++r) {
      int b = bg * 4 + r;
      float cv = uniform ? 0.01f : c[((size_t)b * 100 + o) * 1152 + gi];
      const float4* up = (const float4*)(u + ((size_t)b * 1152 + gi) * 8);
      float4 u0 = up[0], u1 = up[1];
      cu[r][0] = cv * u0.x; cu[r][1] = cv * u0.y; cu[r][2] = cv * u0.z; cu[r][3] = cv * u0.w;
      cu[r][4] = cv * u1.x; cu[r][5] = cv * u1.y; cu[r][6] = cv * u1.z; cu[r][7] = cv * u1.w;
    }
    const float4* Wr = (const float4*)(Wl + ii * 128 + dh * 64);
    #pragma unroll
    for (int d = 0; d < 8; ++d) {
      float4 wa = Wr[d * 2], wb = Wr[d * 2 + 1];
      #pragma unroll
      for (int r = 0; r < 4; ++r) {
        acc[r][d] += wa.x * cu[r][0] + wa.y * cu[r][1] + wa.z * cu[r][2] + wa.w * cu[r][3]
                   + wb.x * cu[r][4] + wb.y * cu[r][5] + wb.z * cu[r][6] + wb.w * cu[r][7];
      }
    }
  }
  // cross-wave reduction: reuse Wl (swizzled to avoid bank conflicts)
  __syncthreads();
  #pragma unroll
  for (int r = 0; r < 4; ++r)
    #pragma unroll
    for (int d = 0; d < 8; ++d) {
      int rd = r * 8 + d;
      Wl[wave * 2048 + lane * 32 + ((rd + lane) & 31)] = acc[r][d];
    }
  __syncthreads();
  #pragma unroll
  for (int j0 = 0; j0 < 8; ++j0) {
    int j = t * 8 + j0;                             // 0..2047
    int ln = j >> 5, rd = j & 31;
    int sw = ln * 32 + ((rd + ln) & 31);
    float vsum = Wl[sw] + Wl[2048 + sw] + Wl[4096 + sw] + Wl[6144 + sw];
    int r = rd >> 3, d = rd & 7;
    int dh2 = ln >> 5, bg2 = ln & 31;
    int b = bg2 * 4 + r;
    atomicAdd(s + ((size_t)b * 100 + o) * 16 + dh2 * 8 + d, vsum);
  }
}

// ---------- routing b-update (256 thr): waves split the b loop ----------
__global__ __launch_bounds__(256) void caps_bupdate(
    const float* __restrict__ W, const float* __restrict__ u,
    const float* __restrict__ v, float* __restrict__ blog)
{
  int o = blockIdx.x, ic = blockIdx.y, t = threadIdx.x;
  int wave = t >> 6, lane = t & 63;
  int gi = ic * 64 + lane;
  const float4* Wg = (const float4*)(W + ((size_t)o * 1152 + gi) * 128);
  float4 w[32];
  #pragma unroll
  for (int l = 0; l < 32; ++l) w[l] = Wg[l];
  for (int bi = 0; bi < 32; ++bi) {
    int b = wave * 32 + bi;
    const float* vp = v + ((size_t)b * 100 + o) * 16;  // wave-uniform -> s_load
    float te[8] = {0, 0, 0, 0, 0, 0, 0, 0};
    #pragma unroll
    for (int d = 0; d < 16; ++d) {
      float vv = vp[d];
      float4 wa = w[d * 2], wb = w[d * 2 + 1];
      te[0] += wa.x * vv; te[1] += wa.y * vv; te[2] += wa.z * vv; te[3] += wa.w * vv;
      te[4] += wb.x * vv; te[5] += wb.y * vv; te[6] += wb.z * vv; te[7] += wb.w * vv;
    }
    const float4* up = (const float4*)(u + ((size_t)b * 1152 + gi) * 8);
    float4 u0 = up[0], u1 = up[1];
    float dot = te[0] * u0.x + te[1] * u0.y + te[2] * u0.z + te[3] * u0.w
              + te[4] * u1.x + te[5] * u1.y + te[6] * u1.z + te[7] * u1.w;
    blog[((size_t)b * 100 + o) * 1152 + gi] += dot;
  }
}

// ---------- softmax over o (=100) per (b,i) ----------
__global__ __launch_bounds__(256) void caps_softmax(
    const float* __restrict__ blog, float* __restrict__ c)
{
  int idx = blockIdx.x * 256 + threadIdx.x;        // (b,i) over 128*1152
  if (idx >= 128 * 1152) return;
  int b = idx / 1152, i = idx % 1152;
  const float* bp = blog + (size_t)b * 115200 + i;
  float m = -3.4e38f;
  for (int o = 0; o < 100; ++o) m = fmaxf(m, bp[(size_t)o * 1152]);
  float sum = 0.f;
  for (int o = 0; o < 100; ++o) sum += __expf(bp[(size_t)o * 1152] - m);
  float inv = 1.f / sum;
  float* cp = c + (size_t)b * 115200 + i;
  for (int o = 0; o < 100; ++o) cp[(size_t)o * 1152] = __expf(bp[(size_t)o * 1152] - m) * inv;
}

// ---------- split-K FC GEMM with prefetch pipeline; partials atomicAdd'ed ----------
__global__ __launch_bounds__(256) void fc_gemm_sk(
    const float* __restrict__ A, const float* __restrict__ W,
    float* __restrict__ C, int K, int N, int KC)
{
  __shared__ __align__(16) float As[16][72];
  __shared__ __align__(16) float Ws[16][64];
  int n0 = blockIdx.x * 64, m0 = blockIdx.y * 64;
  int kbeg = blockIdx.z * KC, kend = kbeg + KC;
  int t = threadIdx.x;
  int tc = t & 15, tr = t >> 4;

  auto loadA = [&](int k0, float* r) {
    #pragma unroll
    for (int i = 0; i < 4; ++i) {
      int l = t + i * 256; int kk = l & 15, mm = l >> 4;
      r[i] = A[(size_t)(m0 + mm) * K + k0 + kk];
    }
  };
  auto loadW = [&](int k0, float* r) {
    #pragma unroll
    for (int i = 0; i < 4; ++i) {
      int l = t + i * 256; int nn = l & 63, kk = l >> 6;
      r[i] = W[(size_t)(k0 + kk) * N + n0 + nn];
    }
  };

  float pa[4], pw[4];
  loadA(kbeg, pa); loadW(kbeg, pw);
  float acc[4][4] = {};
  for (int k0 = kbeg; k0 < kend; k0 += 16) {
    if (k0 > kbeg) __syncthreads();
    #pragma unroll
    for (int i = 0; i < 4; ++i) { int l = t + i * 256; As[l & 15][l >> 4] = pa[i]; }
    #pragma unroll
    for (int i = 0; i < 4; ++i) { int l = t + i * 256; Ws[l >> 6][l & 63] = pw[i]; }
    __syncthreads();
    if (k0 + 16 < kend) { loadA(k0 + 16, pa); loadW(k0 + 16, pw); }
    #pragma unroll
    for (int kk = 0; kk < 16; ++kk) {
      float4 a4 = *(const float4*)&As[kk][tr * 4];
      float4 w4 = *(const float4*)&Ws[kk][tc * 4];
      acc[0][0] += a4.x * w4.x; acc[0][1] += a4.x * w4.y; acc[0][2] += a4.x * w4.z; acc[0][3] += a4.x * w4.w;
      acc[1][0] += a4.y * w4.x; acc[1][1] += a4.y * w4.y; acc[1][2] += a4.y * w4.z; acc[1][3] += a4.y * w4.w;
      acc[2][0] += a4.z * w4.x; acc[2][1] += a4.z * w4.y; acc[2][2] += a4.z * w4.z; acc[2][3] += a4.z * w4.w;
      acc[3][0] += a4.w * w4.x; acc[3][1] += a4.w * w4.y; acc[3][2] += a4.w * w4.z; acc[3][3] += a4.w * w4.w;
    }
  }
  #pragma unroll
  for (int r = 0; r < 4; ++r) {
    int m = m0 + tr * 4 + r;
    #pragma unroll
    for (int cl = 0; cl < 4; ++cl) {
      int n = n0 + tc * 4 + cl;
      atomicAdd(C + (size_t)m * N + n, acc[r][cl]);
    }
  }
}

// ---------- bias + optional relu, in place ----------
__global__ __launch_bounds__(256) void bias_act_k(
    float* __restrict__ C, const float* __restrict__ bias, int N, int total, int relu)
{
  int idx = blockIdx.x * 256 + threadIdx.x;
  if (idx >= total) return;
  float vv = C[idx] + bias[idx % N];
  if (relu) vv = fmaxf(vv, 0.f);
  C[idx] = vv;
}

// ---------- fc3: seed bias, then split-K accumulate ----------
__global__ __launch_bounds__(128) void fc3_seed(
    const float* __restrict__ bias, float* __restrict__ out)
{
  int idx = blockIdx.x * 128 + threadIdx.x;        // 12800
  if (idx < 12800) out[idx] = bias[idx % 100];
}

__global__ __launch_bounds__(128) void fc3_sk(
    const float* __restrict__ A, const float* __restrict__ W,
    float* __restrict__ out)
{
  __shared__ float Al[1024];
  int m = blockIdx.x, z = blockIdx.y, t = threadIdx.x;
  int kbeg = z * 1024;
  const float* ap = A + (size_t)m * 4096 + kbeg;
  for (int l = t; l < 1024; l += 128) Al[l] = ap[l];
  __syncthreads();
  if (t < 100) {
    float acc = 0.f;
    const float* wp = W + (size_t)kbeg * 100 + t;
    #pragma unroll 8
    for (int k = 0; k < 1024; ++k) acc += Al[k] * wp[(size_t)k * 100];
    atomicAdd(out + m * 100 + t, acc);
  }
}

// ============================================================================
extern "C" void kernel_launch(void* const* d_in, const int* in_sizes, int n_in,
                              void* d_out, int out_size, void* d_ws, size_t ws_size,
                              hipStream_t stream)
{
  (void)in_sizes; (void)n_in; (void)out_size; (void)ws_size;
  const float* x   = (const float*)d_in[0];
  const float* cw1 = (const float*)d_in[1];
  const float* cb1 = (const float*)d_in[2];
  const float* cw2 = (const float*)d_in[3];
  const float* cb2 = (const float*)d_in[4];
  const float* cw3 = (const float*)d_in[5];
  const float* cb3 = (const float*)d_in[6];
  const float* pw  = (const float*)d_in[7];
  const float* pb  = (const float*)d_in[8];
  const float* Wc  = (const float*)d_in[9];
  const float* fw1 = (const float*)d_in[10];
  const float* fb1 = (const float*)d_in[11];
  const float* fw2 = (const float*)d_in[12];
  const float* fb2 = (const float*)d_in[13];
  const float* fw3 = (const float*)d_in[14];
  const float* fb3 = (const float*)d_in[15];
  float* ws = (float*)d_ws;

  const size_t OFF_A  = 0;          // 12,582,912 : h1 / h2 / h3 ; later blog
  const size_t OFF_B  = 12582912;   //  3,145,728 : h1p / h2p
  const size_t OFF_U  = 15728640;   //  1,179,648 : u [128,1152,8]
  const size_t OFF_P  = 16908288;   //  1,179,648 : p [128,256,36]
  const size_t OFF_C  = 18087936;   // 14,745,600 : c [128,100,1152]
  const size_t OFF_V  = 32833536;   //    204,800 : v [128,100,16]
  const size_t OFF_S  = 33038336;   //    204,800 : s [128,100,16]
  const size_t OFF_F1 = 33243136;   //    524,288 : f1 [128,4096]
  const size_t OFF_F2 = 33767424;   //    524,288 : f2 [128,4096]

  float* A    = ws + OFF_A;
  float* Bf   = ws + OFF_B;
  float* u    = ws + OFF_U;
  float* p    = ws + OFF_P;
  float* c    = ws + OFF_C;
  float* v    = ws + OFF_V;
  float* s    = ws + OFF_S;
  float* f1   = ws + OFF_F1;
  float* f2   = ws + OFF_F2;
  float* blog = ws + OFF_A;

  // zero accumulation targets up front (stream-ordered, before their producers)
  hipMemsetAsync(p,  0, (size_t)1179648 * 4, stream);
  hipMemsetAsync(f1, 0, (size_t)524288 * 4, stream);
  hipMemsetAsync(f2, 0, (size_t)524288 * 4, stream);

  // Backbone
  conv1_k<<<49152, 256, 0, stream>>>(x, cw1, cb1, A);                 // [128,96,32,32]
  maxpool_k<<<12288, 256, 0, stream>>>(A, Bf, 32);                    // [128,96,16,16]
  convgemm_k<96, 16, 1, 16, false><<<dim3(512, 4), 256, 0, stream>>>(Bf, cw2, cb2, A, 256, 1, 0);
  maxpool_k<<<8192, 256, 0, stream>>>(A, Bf, 16);                     // [128,256,8,8]
  convgemm_k<256, 8, 1, 8, false><<<dim3(128, 6), 256, 0, stream>>>(Bf, cw3, cb3, A, 384, 1, 0);
  // pcaps split-K x4 (K=3456 -> KC=864), bias added in squash8
  convgemm_k<384, 8, 0, 6, true><<<dim3(72, 4, 4), 256, 0, stream>>>(A, pw, pb, p, 256, 0, 864);
  squash8_k<<<576, 256, 0, stream>>>(p, pb, u);                       // [128,1152,8]

  // Dynamic routing (3 iterations), x_hat recomputed on the fly
  hipMemsetAsync(blog, 0, (size_t)14745600 * 4, stream);
  for (int r = 0; r < 3; ++r) {
    hipMemsetAsync(s, 0, (size_t)204800 * 4, stream);
    if (r == 0) {
      caps_spass<<<dim3(100, 18), 256, 0, stream>>>(Wc, u, u /*dummy*/, s, 1);
    } else {
      caps_softmax<<<576, 256, 0, stream>>>(blog, c);
      caps_spass<<<dim3(100, 18), 256, 0, stream>>>(Wc, u, c, s, 0);
    }
    caps_squash16<<<50, 256, 0, stream>>>(s, v);
    if (r < 2)
      caps_bupdate<<<dim3(100, 18), 256, 0, stream>>>(Wc, u, v, blog);
  }

  // FC head; v is already [128,1600] flat
  fc_gemm_sk<<<dim3(64, 2, 4), 256, 0, stream>>>(v,  fw1, f1, 1600, 4096, 400);
  bias_act_k<<<2048, 256, 0, stream>>>(f1, fb1, 4096, 524288, 1);
  fc_gemm_sk<<<dim3(64, 2, 8), 256, 0, stream>>>(f1, fw2, f2, 4096, 4096, 512);
  bias_act_k<<<2048, 256, 0, stream>>>(f2, fb2, 4096, 524288, 1);
  fc3_seed<<<100, 128, 0, stream>>>(fb3, (float*)d_out);
  fc3_sk<<<dim3(128, 4), 128, 0, stream>>>(f2, fw3, (float*)d_out);
}

// Round 4
// 2335.795 us; speedup vs baseline: 1.7293x; 1.1892x over previous
//
#include <hip/hip_runtime.h>
#include <cstddef>

// ============================================================================
// AlexCapsNet CIFAR-100 forward, fp32. Round 4: routing layout round.
// All routing operands batch-innermost: u_t[i,e,b], c_t[o,i,b], blog_t[o,i,b],
// v_t[o,d,b] -> lane=b gives coalesced loads; spass/bupdate VGPR ~50, no
// barrier in inner loop.
// ============================================================================

// ---------- conv1: direct 3->96 k3 s1 p1 + relu ----------
__global__ __launch_bounds__(256) void conv1_k(
    const float* __restrict__ x, const float* __restrict__ wt,
    const float* __restrict__ bias, float* __restrict__ out)
{
  int idx = blockIdx.x * 256 + threadIdx.x;          // [b,co,h,w] over 128*96*32*32
  int w = idx & 31, h = (idx >> 5) & 31;
  int t2 = idx >> 10;
  int co = t2 % 96, b = t2 / 96;
  float acc = bias[co];
  #pragma unroll
  for (int ci = 0; ci < 3; ++ci) {
    const float* xp = x + ((size_t)(b * 3 + ci) << 10);
    const float* wp = wt + (size_t)(co * 3 + ci) * 9;
    #pragma unroll
    for (int dh = 0; dh < 3; ++dh) {
      int ih = h + dh - 1;
      if (ih < 0 || ih > 31) continue;
      #pragma unroll
      for (int dw = 0; dw < 3; ++dw) {
        int iw = w + dw - 1;
        if (iw < 0 || iw > 31) continue;
        acc += xp[(ih << 5) + iw] * wp[dh * 3 + dw];
      }
    }
  }
  out[idx] = fmaxf(acc, 0.f);
}

// ---------- maxpool k3 s2 p1 ----------
__global__ __launch_bounds__(256) void maxpool_k(
    const float* __restrict__ in, float* __restrict__ out, int H)
{
  int Ho = H >> 1;
  int idx = blockIdx.x * 256 + threadIdx.x;
  int wo = idx % Ho;
  int t2 = idx / Ho;
  int ho = t2 % Ho;
  int bc = t2 / Ho;
  const float* ip = in + (size_t)bc * H * H;
  float m = -3.4e38f;
  #pragma unroll
  for (int dh = 0; dh < 3; ++dh) {
    int ih = 2 * ho - 1 + dh;
    if (ih < 0 || ih >= H) continue;
    #pragma unroll
    for (int dw = 0; dw < 3; ++dw) {
      int iw = 2 * wo - 1 + dw;
      if (iw < 0 || iw >= H) continue;
      m = fmaxf(m, ip[ih * H + iw]);
    }
  }
  out[idx] = m;
}

// ---------- conv as GEMM, on-the-fly im2col, register-prefetch pipeline ----------
template <int CI, int H, int PAD, int WO, bool SPLIT>
__global__ __launch_bounds__(256) void convgemm_k(
    const float* __restrict__ in, const float* __restrict__ wt,
    const float* __restrict__ bias, float* __restrict__ out,
    int CO, int relu, int KC)
{
  constexpr int K = CI * 9;
  constexpr int NPIX = WO * WO;
  __shared__ __align__(16) float As[16][72];
  __shared__ __align__(16) float Bs[16][64];
  int n0 = blockIdx.x * 64, m0 = blockIdx.y * 64;
  int kbeg = SPLIT ? blockIdx.z * KC : 0;
  int kend = SPLIT ? kbeg + KC : K;
  int t = threadIdx.x;
  int tc = t & 15, tr = t >> 4;

  auto loadA = [&](int k0, float* r) {
    #pragma unroll
    for (int i = 0; i < 4; ++i) {
      int l = t + i * 256; int kk = l & 15, mm = l >> 4;
      r[i] = wt[(size_t)(m0 + mm) * K + k0 + kk];
    }
  };
  auto loadB = [&](int k0, float* r) {
    #pragma unroll
    for (int i = 0; i < 4; ++i) {
      int l = t + i * 256; int nn = l & 63, kk = l >> 6;
      int k = k0 + kk;
      int ci = k / 9, rr = k - ci * 9;
      int dh = rr / 3, dw = rr - dh * 3;
      int n = n0 + nn;
      int b = n / NPIX, xy = n - b * NPIX;
      int ho = xy / WO, wo = xy - ho * WO;
      int ih = ho + dh - PAD, iw = wo + dw - PAD;
      r[i] = (ih >= 0 && ih < H && iw >= 0 && iw < H)
               ? in[((size_t)(b * CI + ci) * H + ih) * H + iw] : 0.f;
    }
  };

  float pa[4], pb[4];
  loadA(kbeg, pa); loadB(kbeg, pb);
  float acc[4][4] = {};
  for (int k0 = kbeg; k0 < kend; k0 += 16) {
    if (k0 > kbeg) __syncthreads();
    #pragma unroll
    for (int i = 0; i < 4; ++i) { int l = t + i * 256; As[l & 15][l >> 4] = pa[i]; }
    #pragma unroll
    for (int i = 0; i < 4; ++i) { int l = t + i * 256; Bs[l >> 6][l & 63] = pb[i]; }
    __syncthreads();
    if (k0 + 16 < kend) { loadA(k0 + 16, pa); loadB(k0 + 16, pb); }
    #pragma unroll
    for (int kk = 0; kk < 16; ++kk) {
      float4 a4 = *(const float4*)&As[kk][tr * 4];
      float4 w4 = *(const float4*)&Bs[kk][tc * 4];
      acc[0][0] += a4.x * w4.x; acc[0][1] += a4.x * w4.y; acc[0][2] += a4.x * w4.z; acc[0][3] += a4.x * w4.w;
      acc[1][0] += a4.y * w4.x; acc[1][1] += a4.y * w4.y; acc[1][2] += a4.y * w4.z; acc[1][3] += a4.y * w4.w;
      acc[2][0] += a4.z * w4.x; acc[2][1] += a4.z * w4.y; acc[2][2] += a4.z * w4.z; acc[2][3] += a4.z * w4.w;
      acc[3][0] += a4.w * w4.x; acc[3][1] += a4.w * w4.y; acc[3][2] += a4.w * w4.z; acc[3][3] += a4.w * w4.w;
    }
  }
  #pragma unroll
  for (int r = 0; r < 4; ++r) {
    int m = m0 + tr * 4 + r;
    float bv = SPLIT ? 0.f : bias[m];
    #pragma unroll
    for (int cl = 0; cl < 4; ++cl) {
      int n = n0 + tc * 4 + cl;
      int b = n / NPIX, xy = n - b * NPIX;
      size_t oidx = ((size_t)b * CO + m) * NPIX + xy;
      if (SPLIT) {
        atomicAdd(out + oidx, acc[r][cl]);
      } else {
        float vv = acc[r][cl] + bv;
        if (relu) vv = fmaxf(vv, 0.f);
        out[oidx] = vv;
      }
    }
  }
}

// ---------- squash8 + pcaps bias; p[b,256,36] partials -> u_t[i,e,b] ----------
__global__ __launch_bounds__(256) void squash8_k(
    const float* __restrict__ p, const float* __restrict__ pb,
    float* __restrict__ ut)
{
  int idx = blockIdx.x * 256 + threadIdx.x;        // 147456: b = idx&127, i = idx>>7
  if (idx >= 147456) return;
  int b = idx & 127, i = idx >> 7;
  const float4* pp = (const float4*)(p + ((size_t)b * 1152 + i) * 8);
  float4 a = pp[0], bb = pp[1];
  float pv[8] = {a.x, a.y, a.z, a.w, bb.x, bb.y, bb.z, bb.w};
  int f0 = i * 8;
  #pragma unroll
  for (int e = 0; e < 8; ++e) pv[e] += pb[(f0 + e) / 36];
  float n2 = 0.f;
  #pragma unroll
  for (int e = 0; e < 8; ++e) n2 += pv[e] * pv[e];
  float sc = (n2 / (1.f + n2)) * rsqrtf(n2 + 1e-8f);
  #pragma unroll
  for (int e = 0; e < 8; ++e)
    ut[(size_t)i * 1024 + e * 128 + b] = pv[e] * sc;   // coalesced over b
}

// ---------- squash16: s[b,o,16] -> v[b,o,16] (FC layout) + v_t[o,d,b] ----------
__global__ __launch_bounds__(256) void caps_squash16(
    const float* __restrict__ s, float* __restrict__ v, float* __restrict__ vt)
{
  int idx = blockIdx.x * 256 + threadIdx.x;        // (b,o) over 128*100
  if (idx >= 12800) return;
  int b = idx / 100, o = idx % 100;
  const float4* sp = (const float4*)(s + (size_t)idx * 16);
  float4 a = sp[0], bb = sp[1], c = sp[2], d = sp[3];
  float n2 = a.x * a.x + a.y * a.y + a.z * a.z + a.w * a.w +
             bb.x * bb.x + bb.y * bb.y + bb.z * bb.z + bb.w * bb.w +
             c.x * c.x + c.y * c.y + c.z * c.z + c.w * c.w +
             d.x * d.x + d.y * d.y + d.z * d.z + d.w * d.w;
  float sc = (n2 / (1.f + n2)) * rsqrtf(n2 + 1e-8f);
  float vv[16] = {a.x, a.y, a.z, a.w, bb.x, bb.y, bb.z, bb.w,
                  c.x, c.y, c.z, c.w, d.x, d.y, d.z, d.w};
  float4* vp = (float4*)(v + (size_t)idx * 16);
  float4 o0 = {vv[0] * sc, vv[1] * sc, vv[2] * sc, vv[3] * sc};
  float4 o1 = {vv[4] * sc, vv[5] * sc, vv[6] * sc, vv[7] * sc};
  float4 o2 = {vv[8] * sc, vv[9] * sc, vv[10] * sc, vv[11] * sc};
  float4 o3 = {vv[12] * sc, vv[13] * sc, vv[14] * sc, vv[15] * sc};
  vp[0] = o0; vp[1] = o1; vp[2] = o2; vp[3] = o3;
  #pragma unroll
  for (int dd = 0; dd < 16; ++dd)
    vt[((size_t)o * 16 + dd) * 128 + b] = vv[dd] * sc;
}

// ---------- routing s-pass: lane=b coalesced, W chunk broadcast from LDS ----------
// s[b,o,d] += sum_{i in chunk,e} c_t[o,i,b] * W[o,i,d,e] * u_t[i,e,b]
__global__ __launch_bounds__(256) void caps_spass(
    const float* __restrict__ W, const float* __restrict__ ut,
    const float* __restrict__ ct, float* __restrict__ s, int uniform)
{
  __shared__ __align__(16) float Wl[8192];
  int o = blockIdx.x, ic = blockIdx.y, t = threadIdx.x;
  const float4* Wg = (const float4*)(W + ((size_t)o * 1152 + (size_t)ic * 64) * 128);
  float4* Wl4 = (float4*)Wl;
  for (int l = t; l < 2048; l += 256) Wl4[l] = Wg[l];
  __syncthreads();
  int b = t & 127, dh = t >> 7;                    // dh: d 0-7 or 8-15
  float acc[8] = {};
  for (int ii = 0; ii < 64; ++ii) {
    int gi = ic * 64 + ii;
    float cv = uniform ? 0.01f : ct[((size_t)o * 1152 + gi) * 128 + b];
    float cu[8];
    #pragma unroll
    for (int e = 0; e < 8; ++e)
      cu[e] = cv * ut[(size_t)gi * 1024 + e * 128 + b];  // coalesced
    const float4* Wr = (const float4*)(Wl + ii * 128 + dh * 64);
    #pragma unroll
    for (int d = 0; d < 8; ++d) {
      float4 wa = Wr[d * 2], wb = Wr[d * 2 + 1];   // wave-uniform -> broadcast
      acc[d] += wa.x * cu[0] + wa.y * cu[1] + wa.z * cu[2] + wa.w * cu[3]
              + wb.x * cu[4] + wb.y * cu[5] + wb.z * cu[6] + wb.w * cu[7];
    }
  }
  #pragma unroll
  for (int d = 0; d < 8; ++d)
    atomicAdd(s + ((size_t)b * 100 + o) * 16 + dh * 8 + d, acc[d]);
}

// ---------- routing b-update: blog_t[o,i,b] += sum_{d,e} W[o,i,d,e] u_t[i,e,b] v_t[o,d,b]
__global__ __launch_bounds__(256) void caps_bupdate(
    const float* __restrict__ W, const float* __restrict__ ut,
    const float* __restrict__ vt, float* __restrict__ blogt)
{
  __shared__ __align__(16) float Wl[8192];
  int o = blockIdx.x, ic = blockIdx.y, t = threadIdx.x;
  const float4* Wg = (const float4*)(W + ((size_t)o * 1152 + (size_t)ic * 64) * 128);
  float4* Wl4 = (float4*)Wl;
  for (int l = t; l < 2048; l += 256) Wl4[l] = Wg[l];
  int b = t & 127, ih = t >> 7;                    // ih: i-half of the 64-chunk
  float vr[16];
  #pragma unroll
  for (int d = 0; d < 16; ++d)
    vr[d] = vt[((size_t)o * 16 + d) * 128 + b];    // coalesced, hoisted
  __syncthreads();
  for (int jj = 0; jj < 32; ++jj) {
    int li = ih * 32 + jj;
    int gi = ic * 64 + li;
    const float4* Wr = (const float4*)(Wl + li * 128);
    float T[8] = {};
    #pragma unroll
    for (int d = 0; d < 16; ++d) {
      float4 wa = Wr[d * 2], wb = Wr[d * 2 + 1];   // wave-uniform -> broadcast
      float vv = vr[d];
      T[0] += wa.x * vv; T[1] += wa.y * vv; T[2] += wa.z * vv; T[3] += wa.w * vv;
      T[4] += wb.x * vv; T[5] += wb.y * vv; T[6] += wb.z * vv; T[7] += wb.w * vv;
    }
    float dot = 0.f;
    #pragma unroll
    for (int e = 0; e < 8; ++e)
      dot += T[e] * ut[(size_t)gi * 1024 + e * 128 + b];  // coalesced
    size_t bi = ((size_t)o * 1152 + gi) * 128 + b;
    blogt[bi] += dot;                               // coalesced RMW
  }
}

// ---------- softmax over o per (i,b), transposed layouts ----------
__global__ __launch_bounds__(256) void caps_softmax(
    const float* __restrict__ blogt, float* __restrict__ ct)
{
  int idx = blockIdx.x * 256 + threadIdx.x;        // (i,b) over 147456
  if (idx >= 147456) return;
  const float* bp = blogt + idx;
  float m = -3.4e38f;
  for (int o = 0; o < 100; ++o) m = fmaxf(m, bp[(size_t)o * 147456]);
  float sum = 0.f;
  for (int o = 0; o < 100; ++o) sum += __expf(bp[(size_t)o * 147456] - m);
  float inv = 1.f / sum;
  for (int o = 0; o < 100; ++o)
    ct[(size_t)o * 147456 + idx] = __expf(bp[(size_t)o * 147456] - m) * inv;
}

// ---------- split-K FC GEMM with prefetch pipeline; partials atomicAdd'ed ----------
__global__ __launch_bounds__(256) void fc_gemm_sk(
    const float* __restrict__ A, const float* __restrict__ W,
    float* __restrict__ C, int K, int N, int KC)
{
  __shared__ __align__(16) float As[16][72];
  __shared__ __align__(16) float Ws[16][64];
  int n0 = blockIdx.x * 64, m0 = blockIdx.y * 64;
  int kbeg = blockIdx.z * KC, kend = kbeg + KC;
  int t = threadIdx.x;
  int tc = t & 15, tr = t >> 4;

  auto loadA = [&](int k0, float* r) {
    #pragma unroll
    for (int i = 0; i < 4; ++i) {
      int l = t + i * 256; int kk = l & 15, mm = l >> 4;
      r[i] = A[(size_t)(m0 + mm) * K + k0 + kk];
    }
  };
  auto loadW = [&](int k0, float* r) {
    #pragma unroll
    for (int i = 0; i < 4; ++i) {
      int l = t + i * 256; int nn = l & 63, kk = l >> 6;
      r[i] = W[(size_t)(k0 + kk) * N + n0 + nn];
    }
  };

  float pa[4], pw[4];
  loadA(kbeg, pa); loadW(kbeg, pw);
  float acc[4][4] = {};
  for (int k0 = kbeg; k0 < kend; k0 += 16) {
    if (k0 > kbeg) __syncthreads();
    #pragma unroll
    for (int i = 0; i < 4; ++i) { int l = t + i * 256; As[l & 15][l >> 4] = pa[i]; }
    #pragma unroll
    for (int i = 0; i < 4; ++i) { int l = t + i * 256; Ws[l >> 6][l & 63] = pw[i]; }
    __syncthreads();
    if (k0 + 16 < kend) { loadA(k0 + 16, pa); loadW(k0 + 16, pw); }
    #pragma unroll
    for (int kk = 0; kk < 16; ++kk) {
      float4 a4 = *(const float4*)&As[kk][tr * 4];
      float4 w4 = *(const float4*)&Ws[kk][tc * 4];
      acc[0][0] += a4.x * w4.x; acc[0][1] += a4.x * w4.y; acc[0][2] += a4.x * w4.z; acc[0][3] += a4.x * w4.w;
      acc[1][0] += a4.y * w4.x; acc[1][1] += a4.y * w4.y; acc[1][2] += a4.y * w4.z; acc[1][3] += a4.y * w4.w;
      acc[2][0] += a4.z * w4.x; acc[2][1] += a4.z * w4.y; acc[2][2] += a4.z * w4.z; acc[2][3] += a4.z * w4.w;
      acc[3][0] += a4.w * w4.x; acc[3][1] += a4.w * w4.y; acc[3][2] += a4.w * w4.z; acc[3][3] += a4.w * w4.w;
    }
  }
  #pragma unroll
  for (int r = 0; r < 4; ++r) {
    int m = m0 + tr * 4 + r;
    #pragma unroll
    for (int cl = 0; cl < 4; ++cl) {
      int n = n0 + tc * 4 + cl;
      atomicAdd(C + (size_t)m * N + n, acc[r][cl]);
    }
  }
}

// ---------- bias + optional relu, in place ----------
__global__ __launch_bounds__(256) void bias_act_k(
    float* __restrict__ C, const float* __restrict__ bias, int N, int total, int relu)
{
  int idx = blockIdx.x * 256 + threadIdx.x;
  if (idx >= total) return;
  float vv = C[idx] + bias[idx % N];
  if (relu) vv = fmaxf(vv, 0.f);
  C[idx] = vv;
}

// ---------- fc3 ----------
__global__ __launch_bounds__(128) void fc3_seed(
    const float* __restrict__ bias, float* __restrict__ out)
{
  int idx = blockIdx.x * 128 + threadIdx.x;        // 12800
  if (idx < 12800) out[idx] = bias[idx % 100];
}

__global__ __launch_bounds__(128) void fc3_sk(
    const float* __restrict__ A, const float* __restrict__ W,
    float* __restrict__ out)
{
  __shared__ float Al[1024];
  int m = blockIdx.x, z = blockIdx.y, t = threadIdx.x;
  int kbeg = z * 1024;
  const float* ap = A + (size_t)m * 4096 + kbeg;
  for (int l = t; l < 1024; l += 128) Al[l] = ap[l];
  __syncthreads();
  if (t < 100) {
    float acc = 0.f;
    const float* wp = W + (size_t)kbeg * 100 + t;
    #pragma unroll 8
    for (int k = 0; k < 1024; ++k) acc += Al[k] * wp[(size_t)k * 100];
    atomicAdd(out + m * 100 + t, acc);
  }
}

// ============================================================================
extern "C" void kernel_launch(void* const* d_in, const int* in_sizes, int n_in,
                              void* d_out, int out_size, void* d_ws, size_t ws_size,
                              hipStream_t stream)
{
  (void)in_sizes; (void)n_in; (void)out_size; (void)ws_size;
  const float* x   = (const float*)d_in[0];
  const float* cw1 = (const float*)d_in[1];
  const float* cb1 = (const float*)d_in[2];
  const float* cw2 = (const float*)d_in[3];
  const float* cb2 = (const float*)d_in[4];
  const float* cw3 = (const float*)d_in[5];
  const float* cb3 = (const float*)d_in[6];
  const float* pw  = (const float*)d_in[7];
  const float* pb  = (const float*)d_in[8];
  const float* Wc  = (const float*)d_in[9];
  const float* fw1 = (const float*)d_in[10];
  const float* fb1 = (const float*)d_in[11];
  const float* fw2 = (const float*)d_in[12];
  const float* fb2 = (const float*)d_in[13];
  const float* fw3 = (const float*)d_in[14];
  const float* fb3 = (const float*)d_in[15];
  float* ws = (float*)d_ws;

  const size_t OFF_A  = 0;          // 12,582,912 : h1/h2/h3 ; later blog_t [o,i,b]
  const size_t OFF_B  = 12582912;   //  3,145,728 : h1p / h2p
  const size_t OFF_U  = 15728640;   //  1,179,648 : u_t [1152,8,128]
  const size_t OFF_P  = 16908288;   //  1,179,648 : p [128,256,36]; later v_t [100,16,128]
  const size_t OFF_C  = 18087936;   // 14,745,600 : c_t [100,1152,128]
  const size_t OFF_V  = 32833536;   //    204,800 : v [128,100,16]
  const size_t OFF_S  = 33038336;   //    204,800 : s [128,100,16]
  const size_t OFF_F1 = 33243136;   //    524,288 : f1 [128,4096]
  const size_t OFF_F2 = 33767424;   //    524,288 : f2 [128,4096]

  float* A     = ws + OFF_A;
  float* Bf    = ws + OFF_B;
  float* ut    = ws + OFF_U;
  float* p     = ws + OFF_P;
  float* vt    = ws + OFF_P;        // reuses p region after squash8
  float* ct    = ws + OFF_C;
  float* v     = ws + OFF_V;
  float* s     = ws + OFF_S;
  float* f1    = ws + OFF_F1;
  float* f2    = ws + OFF_F2;
  float* blogt = ws + OFF_A;

  // zero accumulation targets up front (stream-ordered, before their producers)
  hipMemsetAsync(p,  0, (size_t)1179648 * 4, stream);
  hipMemsetAsync(f1, 0, (size_t)524288 * 4, stream);
  hipMemsetAsync(f2, 0, (size_t)524288 * 4, stream);

  // Backbone
  conv1_k<<<49152, 256, 0, stream>>>(x, cw1, cb1, A);                 // [128,96,32,32]
  maxpool_k<<<12288, 256, 0, stream>>>(A, Bf, 32);                    // [128,96,16,16]
  convgemm_k<96, 16, 1, 16, false><<<dim3(512, 4), 256, 0, stream>>>(Bf, cw2, cb2, A, 256, 1, 0);
  maxpool_k<<<8192, 256, 0, stream>>>(A, Bf, 16);                     // [128,256,8,8]
  convgemm_k<256, 8, 1, 8, false><<<dim3(128, 6), 256, 0, stream>>>(Bf, cw3, cb3, A, 384, 1, 0);
  // pcaps split-K x4 (K=3456 -> KC=864), bias added in squash8
  convgemm_k<384, 8, 0, 6, true><<<dim3(72, 4, 4), 256, 0, stream>>>(A, pw, pb, p, 256, 0, 864);
  squash8_k<<<576, 256, 0, stream>>>(p, pb, ut);                      // u_t [1152,8,128]

  // Dynamic routing (3 iterations), x_hat recomputed on the fly
  hipMemsetAsync(blogt, 0, (size_t)14745600 * 4, stream);
  for (int r = 0; r < 3; ++r) {
    hipMemsetAsync(s, 0, (size_t)204800 * 4, stream);
    if (r == 0) {
      caps_spass<<<dim3(100, 18), 256, 0, stream>>>(Wc, ut, ut /*dummy*/, s, 1);
    } else {
      caps_softmax<<<576, 256, 0, stream>>>(blogt, ct);
      caps_spass<<<dim3(100, 18), 256, 0, stream>>>(Wc, ut, ct, s, 0);
    }
    caps_squash16<<<50, 256, 0, stream>>>(s, v, vt);
    if (r < 2)
      caps_bupdate<<<dim3(100, 18), 256, 0, stream>>>(Wc, ut, vt, blogt);
  }

  // FC head; v is already [128,1600] flat
  fc_gemm_sk<<<dim3(64, 2, 4), 256, 0, stream>>>(v,  fw1, f1, 1600, 4096, 400);
  bias_act_k<<<2048, 256, 0, stream>>>(f1, fb1, 4096, 524288, 1);
  fc_gemm_sk<<<dim3(64, 2, 8), 256, 0, stream>>>(f1, fw2, f2, 4096, 4096, 512);
  bias_act_k<<<2048, 256, 0, stream>>>(f2, fb2, 4096, 524288, 1);
  fc3_seed<<<100, 128, 0, stream>>>(fb3, (float*)d_out);
  fc3_sk<<<dim3(128, 4), 128, 0, stream>>>(f2, fw3, (float*)d_out);
}

// Round 5
// 1822.141 us; speedup vs baseline: 2.2168x; 1.2819x over previous
//
#include <hip/hip_runtime.h>
#include <cstddef>

// ============================================================================
// AlexCapsNet CIFAR-100 forward. Round 5: all big GEMMs (conv2/conv3/pcaps/
// fc1/fc2) moved to bf16x2-split MFMA (Ah*Bh + Ah*Bl + Al*Bh, fp32 acc ->
// ~fp32 accuracy at MFMA rate). Routing kernels unchanged from round 4.
// ============================================================================

typedef __attribute__((ext_vector_type(8))) short bf8_t;   // 8 bf16 (4 VGPR)
typedef __attribute__((ext_vector_type(4))) float f4_t;    // 4 fp32 acc

// pack 8 fp32 -> 4 dwords of bf16-hi pairs + 4 dwords of bf16-lo pairs
__device__ inline void cvt_hilo8(const float* f, unsigned* h, unsigned* l)
{
  #pragma unroll
  for (int j = 0; j < 4; ++j) {
    unsigned u0 = __float_as_uint(f[2 * j]);
    unsigned u1 = __float_as_uint(f[2 * j + 1]);
    h[j] = (u0 >> 16) | (u1 & 0xFFFF0000u);
    float r0 = f[2 * j]     - __uint_as_float(u0 & 0xFFFF0000u);
    float r1 = f[2 * j + 1] - __uint_as_float(u1 & 0xFFFF0000u);
    l[j] = (__float_as_uint(r0) >> 16) | (__float_as_uint(r1) & 0xFFFF0000u);
  }
}

// ---------- conv1: direct 3->96 k3 s1 p1 + relu ----------
__global__ __launch_bounds__(256) void conv1_k(
    const float* __restrict__ x, const float* __restrict__ wt,
    const float* __restrict__ bias, float* __restrict__ out)
{
  int idx = blockIdx.x * 256 + threadIdx.x;
  int w = idx & 31, h = (idx >> 5) & 31;
  int t2 = idx >> 10;
  int co = t2 % 96, b = t2 / 96;
  float acc = bias[co];
  #pragma unroll
  for (int ci = 0; ci < 3; ++ci) {
    const float* xp = x + ((size_t)(b * 3 + ci) << 10);
    const float* wp = wt + (size_t)(co * 3 + ci) * 9;
    #pragma unroll
    for (int dh = 0; dh < 3; ++dh) {
      int ih = h + dh - 1;
      if (ih < 0 || ih > 31) continue;
      #pragma unroll
      for (int dw = 0; dw < 3; ++dw) {
        int iw = w + dw - 1;
        if (iw < 0 || iw > 31) continue;
        acc += xp[(ih << 5) + iw] * wp[dh * 3 + dw];
      }
    }
  }
  out[idx] = fmaxf(acc, 0.f);
}

// ---------- maxpool k3 s2 p1 ----------
__global__ __launch_bounds__(256) void maxpool_k(
    const float* __restrict__ in, float* __restrict__ out, int H)
{
  int Ho = H >> 1;
  int idx = blockIdx.x * 256 + threadIdx.x;
  int wo = idx % Ho;
  int t2 = idx / Ho;
  int ho = t2 % Ho;
  int bc = t2 / Ho;
  const float* ip = in + (size_t)bc * H * H;
  float m = -3.4e38f;
  #pragma unroll
  for (int dh = 0; dh < 3; ++dh) {
    int ih = 2 * ho - 1 + dh;
    if (ih < 0 || ih >= H) continue;
    #pragma unroll
    for (int dw = 0; dw < 3; ++dw) {
      int iw = 2 * wo - 1 + dw;
      if (iw < 0 || iw >= H) continue;
      m = fmaxf(m, ip[ih * H + iw]);
    }
  }
  out[idx] = m;
}

// ---------- conv as bf16x2-split MFMA GEMM with on-the-fly im2col ----------
// C[m=co][n=b*NPIX+xy], K = CI*9. BM=BN=64, BK=32 fp32. 4 waves in 2x2 grid,
// each wave 32x32 via 2x2 mfma_f32_16x16x32_bf16 subtiles.
// LDS tiles as [k-group(4)][idx(64)] 16B units (8 bf16 each).
template <int CI, int H, int PAD, int WO, bool SPLIT>
__global__ __launch_bounds__(256) void convgemm_mfma(
    const float* __restrict__ in, const float* __restrict__ wt,
    const float* __restrict__ bias, float* __restrict__ out,
    int CO, int relu, int KC)
{
  constexpr int K = CI * 9;
  constexpr int NPIX = WO * WO;
  __shared__ uint4 Ah[256], Al[256], Bh[256], Bl[256];
  int n0 = blockIdx.x * 64, m0 = blockIdx.y * 64;
  int kbeg = SPLIT ? blockIdx.z * KC : 0;
  int kend = SPLIT ? kbeg + KC : K;
  int t = threadIdx.x;
  int lane = t & 63;
  int wave = __builtin_amdgcn_readfirstlane(t >> 6);
  int wm = wave & 1, wn = wave >> 1;
  int lr = lane & 15, lq = lane >> 4;
  int smA = t >> 2, sgA = t & 3;                   // A staging: row m, k-group

  // B staging: n = lane (coalesced), k-group = wave (scalar im2col decomp)
  int nn = n0 + lane;
  int bb = nn / NPIX, xy = nn - bb * NPIX;
  int ho = xy / WO, wo = xy - ho * WO;
  int ih0 = ho - PAD, iw0 = wo - PAD;
  const float* inb = in + (size_t)bb * CI * H * H;

  float fa[8], fb[8];
  auto loadA = [&](int k0) {
    const float4* ap = (const float4*)(wt + (size_t)(m0 + smA) * K + k0 + sgA * 8);
    float4 a0 = ap[0], a1 = ap[1];
    fa[0] = a0.x; fa[1] = a0.y; fa[2] = a0.z; fa[3] = a0.w;
    fa[4] = a1.x; fa[5] = a1.y; fa[6] = a1.z; fa[7] = a1.w;
  };
  auto loadB = [&](int k0) {
    int kb = k0 + wave * 8;                        // scalar
    int ci = kb / 9, rr = kb - ci * 9;
    int dh = rr / 3, dw = rr - dh * 3;
    #pragma unroll
    for (int j = 0; j < 8; ++j) {
      int ih = ih0 + dh, iw = iw0 + dw;
      bool ok = (ih >= 0 && ih < H && iw >= 0 && iw < H);
      fb[j] = ok ? inb[(ci * H + ih) * H + iw] : 0.f;
      if (++dw == 3) { dw = 0; if (++dh == 3) { dh = 0; ++ci; } }
    }
  };

  loadA(kbeg); loadB(kbeg);
  f4_t acc[2][2];
  #pragma unroll
  for (int mt = 0; mt < 2; ++mt)
    #pragma unroll
    for (int nt = 0; nt < 2; ++nt) acc[mt][nt] = (f4_t)0.0f;

  for (int k0 = kbeg; k0 < kend; k0 += 32) {
    if (k0 > kbeg) __syncthreads();
    unsigned ha[4], la[4], hb[4], lb[4];
    cvt_hilo8(fa, ha, la);
    cvt_hilo8(fb, hb, lb);
    Ah[sgA * 64 + smA] = make_uint4(ha[0], ha[1], ha[2], ha[3]);
    Al[sgA * 64 + smA] = make_uint4(la[0], la[1], la[2], la[3]);
    Bh[wave * 64 + lane] = make_uint4(hb[0], hb[1], hb[2], hb[3]);
    Bl[wave * 64 + lane] = make_uint4(lb[0], lb[1], lb[2], lb[3]);
    __syncthreads();
    if (k0 + 32 < kend) { loadA(k0 + 32); loadB(k0 + 32); }
    bf8_t av_h[2], av_l[2], bv_h[2], bv_l[2];
    #pragma unroll
    for (int mt = 0; mt < 2; ++mt) {
      int ui = lq * 64 + wm * 32 + mt * 16 + lr;
      av_h[mt] = *(const bf8_t*)&Ah[ui];
      av_l[mt] = *(const bf8_t*)&Al[ui];
    }
    #pragma unroll
    for (int nt = 0; nt < 2; ++nt) {
      int ui = lq * 64 + wn * 32 + nt * 16 + lr;
      bv_h[nt] = *(const bf8_t*)&Bh[ui];
      bv_l[nt] = *(const bf8_t*)&Bl[ui];
    }
    #pragma unroll
    for (int mt = 0; mt < 2; ++mt)
      #pragma unroll
      for (int nt = 0; nt < 2; ++nt) {
        acc[mt][nt] = __builtin_amdgcn_mfma_f32_16x16x32_bf16(av_h[mt], bv_h[nt], acc[mt][nt], 0, 0, 0);
        acc[mt][nt] = __builtin_amdgcn_mfma_f32_16x16x32_bf16(av_h[mt], bv_l[nt], acc[mt][nt], 0, 0, 0);
        acc[mt][nt] = __builtin_amdgcn_mfma_f32_16x16x32_bf16(av_l[mt], bv_h[nt], acc[mt][nt], 0, 0, 0);
      }
  }
  // epilogue: C/D layout col=lane&15, row=(lane>>4)*4+reg
  #pragma unroll
  for (int mt = 0; mt < 2; ++mt)
    #pragma unroll
    for (int nt = 0; nt < 2; ++nt) {
      #pragma unroll
      for (int r = 0; r < 4; ++r) {
        int m = m0 + wm * 32 + mt * 16 + lq * 4 + r;
        int n = n0 + wn * 32 + nt * 16 + lr;
        int b = n / NPIX, pxy = n - b * NPIX;
        size_t oidx = ((size_t)b * CO + m) * NPIX + pxy;
        if (SPLIT) {
          atomicAdd(out + oidx, acc[mt][nt][r]);
        } else {
          float vv = acc[mt][nt][r] + bias[m];
          if (relu) vv = fmaxf(vv, 0.f);
          out[oidx] = vv;
        }
      }
    }
}

// ---------- FC as bf16x2-split MFMA GEMM, split-K, atomic partials ----------
__global__ __launch_bounds__(256) void fc_mfma(
    const float* __restrict__ A, const float* __restrict__ W,
    float* __restrict__ C, int K, int N, int KC)
{
  __shared__ uint4 Ah[256], Al[256], Bh[256], Bl[256];
  int n0 = blockIdx.x * 64, m0 = blockIdx.y * 64;
  int kbeg = blockIdx.z * KC, kend = kbeg + KC;
  int t = threadIdx.x;
  int lane = t & 63;
  int wave = __builtin_amdgcn_readfirstlane(t >> 6);
  int wm = wave & 1, wn = wave >> 1;
  int lr = lane & 15, lq = lane >> 4;
  int smA = t >> 2, sgA = t & 3;

  float fa[8], fb[8];
  auto loadA = [&](int k0) {
    const float4* ap = (const float4*)(A + (size_t)(m0 + smA) * K + k0 + sgA * 8);
    float4 a0 = ap[0], a1 = ap[1];
    fa[0] = a0.x; fa[1] = a0.y; fa[2] = a0.z; fa[3] = a0.w;
    fa[4] = a1.x; fa[5] = a1.y; fa[6] = a1.z; fa[7] = a1.w;
  };
  auto loadB = [&](int k0) {
    const float* wp = W + (size_t)(k0 + wave * 8) * N + n0 + lane;
    #pragma unroll
    for (int j = 0; j < 8; ++j) fb[j] = wp[(size_t)j * N];
  };

  loadA(kbeg); loadB(kbeg);
  f4_t acc[2][2];
  #pragma unroll
  for (int mt = 0; mt < 2; ++mt)
    #pragma unroll
    for (int nt = 0; nt < 2; ++nt) acc[mt][nt] = (f4_t)0.0f;

  for (int k0 = kbeg; k0 < kend; k0 += 32) {
    if (k0 > kbeg) __syncthreads();
    unsigned ha[4], la[4], hb[4], lb[4];
    cvt_hilo8(fa, ha, la);
    cvt_hilo8(fb, hb, lb);
    Ah[sgA * 64 + smA] = make_uint4(ha[0], ha[1], ha[2], ha[3]);
    Al[sgA * 64 + smA] = make_uint4(la[0], la[1], la[2], la[3]);
    Bh[wave * 64 + lane] = make_uint4(hb[0], hb[1], hb[2], hb[3]);
    Bl[wave * 64 + lane] = make_uint4(lb[0], lb[1], lb[2], lb[3]);
    __syncthreads();
    if (k0 + 32 < kend) { loadA(k0 + 32); loadB(k0 + 32); }
    bf8_t av_h[2], av_l[2], bv_h[2], bv_l[2];
    #pragma unroll
    for (int mt = 0; mt < 2; ++mt) {
      int ui = lq * 64 + wm * 32 + mt * 16 + lr;
      av_h[mt] = *(const bf8_t*)&Ah[ui];
      av_l[mt] = *(const bf8_t*)&Al[ui];
    }
    #pragma unroll
    for (int nt = 0; nt < 2; ++nt) {
      int ui = lq * 64 + wn * 32 + nt * 16 + lr;
      bv_h[nt] = *(const bf8_t*)&Bh[ui];
      bv_l[nt] = *(const bf8_t*)&Bl[ui];
    }
    #pragma unroll
    for (int mt = 0; mt < 2; ++mt)
      #pragma unroll
      for (int nt = 0; nt < 2; ++nt) {
        acc[mt][nt] = __builtin_amdgcn_mfma_f32_16x16x32_bf16(av_h[mt], bv_h[nt], acc[mt][nt], 0, 0, 0);
        acc[mt][nt] = __builtin_amdgcn_mfma_f32_16x16x32_bf16(av_h[mt], bv_l[nt], acc[mt][nt], 0, 0, 0);
        acc[mt][nt] = __builtin_amdgcn_mfma_f32_16x16x32_bf16(av_l[mt], bv_h[nt], acc[mt][nt], 0, 0, 0);
      }
  }
  #pragma unroll
  for (int mt = 0; mt < 2; ++mt)
    #pragma unroll
    for (int nt = 0; nt < 2; ++nt) {
      #pragma unroll
      for (int r = 0; r < 4; ++r) {
        int m = m0 + wm * 32 + mt * 16 + lq * 4 + r;
        int n = n0 + wn * 32 + nt * 16 + lr;
        atomicAdd(C + (size_t)m * N + n, acc[mt][nt][r]);
      }
    }
}

// ---------- squash8 + pcaps bias; p[b,256,36] partials -> u_t[i,e,b] ----------
__global__ __launch_bounds__(256) void squash8_k(
    const float* __restrict__ p, const float* __restrict__ pb,
    float* __restrict__ ut)
{
  int idx = blockIdx.x * 256 + threadIdx.x;
  if (idx >= 147456) return;
  int b = idx & 127, i = idx >> 7;
  const float4* pp = (const float4*)(p + ((size_t)b * 1152 + i) * 8);
  float4 a = pp[0], bb = pp[1];
  float pv[8] = {a.x, a.y, a.z, a.w, bb.x, bb.y, bb.z, bb.w};
  int f0 = i * 8;
  #pragma unroll
  for (int e = 0; e < 8; ++e) pv[e] += pb[(f0 + e) / 36];
  float n2 = 0.f;
  #pragma unroll
  for (int e = 0; e < 8; ++e) n2 += pv[e] * pv[e];
  float sc = (n2 / (1.f + n2)) * rsqrtf(n2 + 1e-8f);
  #pragma unroll
  for (int e = 0; e < 8; ++e)
    ut[(size_t)i * 1024 + e * 128 + b] = pv[e] * sc;
}

// ---------- squash16: s[b,o,16] -> v[b,o,16] + v_t[o,d,b] ----------
__global__ __launch_bounds__(256) void caps_squash16(
    const float* __restrict__ s, float* __restrict__ v, float* __restrict__ vt)
{
  int idx = blockIdx.x * 256 + threadIdx.x;
  if (idx >= 12800) return;
  int b = idx / 100, o = idx % 100;
  const float4* sp = (const float4*)(s + (size_t)idx * 16);
  float4 a = sp[0], bb = sp[1], c = sp[2], d = sp[3];
  float n2 = a.x * a.x + a.y * a.y + a.z * a.z + a.w * a.w +
             bb.x * bb.x + bb.y * bb.y + bb.z * bb.z + bb.w * bb.w +
             c.x * c.x + c.y * c.y + c.z * c.z + c.w * c.w +
             d.x * d.x + d.y * d.y + d.z * d.z + d.w * d.w;
  float sc = (n2 / (1.f + n2)) * rsqrtf(n2 + 1e-8f);
  float vv[16] = {a.x, a.y, a.z, a.w, bb.x, bb.y, bb.z, bb.w,
                  c.x, c.y, c.z, c.w, d.x, d.y, d.z, d.w};
  float4* vp = (float4*)(v + (size_t)idx * 16);
  float4 o0 = {vv[0] * sc, vv[1] * sc, vv[2] * sc, vv[3] * sc};
  float4 o1 = {vv[4] * sc, vv[5] * sc, vv[6] * sc, vv[7] * sc};
  float4 o2 = {vv[8] * sc, vv[9] * sc, vv[10] * sc, vv[11] * sc};
  float4 o3 = {vv[12] * sc, vv[13] * sc, vv[14] * sc, vv[15] * sc};
  vp[0] = o0; vp[1] = o1; vp[2] = o2; vp[3] = o3;
  #pragma unroll
  for (int dd = 0; dd < 16; ++dd)
    vt[((size_t)o * 16 + dd) * 128 + b] = vv[dd] * sc;
}

// ---------- routing s-pass ----------
__global__ __launch_bounds__(256) void caps_spass(
    const float* __restrict__ W, const float* __restrict__ ut,
    const float* __restrict__ ct, float* __restrict__ s, int uniform)
{
  __shared__ __align__(16) float Wl[8192];
  int o = blockIdx.x, ic = blockIdx.y, t = threadIdx.x;
  const float4* Wg = (const float4*)(W + ((size_t)o * 1152 + (size_t)ic * 64) * 128);
  float4* Wl4 = (float4*)Wl;
  for (int l = t; l < 2048; l += 256) Wl4[l] = Wg[l];
  __syncthreads();
  int b = t & 127, dh = t >> 7;
  float acc[8] = {};
  for (int ii = 0; ii < 64; ++ii) {
    int gi = ic * 64 + ii;
    float cv = uniform ? 0.01f : ct[((size_t)o * 1152 + gi) * 128 + b];
    float cu[8];
    #pragma unroll
    for (int e = 0; e < 8; ++e)
      cu[e] = cv * ut[(size_t)gi * 1024 + e * 128 + b];
    const float4* Wr = (const float4*)(Wl + ii * 128 + dh * 64);
    #pragma unroll
    for (int d = 0; d < 8; ++d) {
      float4 wa = Wr[d * 2], wb = Wr[d * 2 + 1];
      acc[d] += wa.x * cu[0] + wa.y * cu[1] + wa.z * cu[2] + wa.w * cu[3]
              + wb.x * cu[4] + wb.y * cu[5] + wb.z * cu[6] + wb.w * cu[7];
    }
  }
  #pragma unroll
  for (int d = 0; d < 8; ++d)
    atomicAdd(s + ((size_t)b * 100 + o) * 16 + dh * 8 + d, acc[d]);
}

// ---------- routing b-update ----------
__global__ __launch_bounds__(256) void caps_bupdate(
    const float* __restrict__ W, const float* __restrict__ ut,
    const float* __restrict__ vt, float* __restrict__ blogt)
{
  __shared__ __align__(16) float Wl[8192];
  int o = blockIdx.x, ic = blockIdx.y, t = threadIdx.x;
  const float4* Wg = (const float4*)(W + ((size_t)o * 1152 + (size_t)ic * 64) * 128);
  float4* Wl4 = (float4*)Wl;
  for (int l = t; l < 2048; l += 256) Wl4[l] = Wg[l];
  int b = t & 127, ih = t >> 7;
  float vr[16];
  #pragma unroll
  for (int d = 0; d < 16; ++d)
    vr[d] = vt[((size_t)o * 16 + d) * 128 + b];
  __syncthreads();
  for (int jj = 0; jj < 32; ++jj) {
    int li = ih * 32 + jj;
    int gi = ic * 64 + li;
    const float4* Wr = (const float4*)(Wl + li * 128);
    float T[8] = {};
    #pragma unroll
    for (int d = 0; d < 16; ++d) {
      float4 wa = Wr[d * 2], wb = Wr[d * 2 + 1];
      float vv = vr[d];
      T[0] += wa.x * vv; T[1] += wa.y * vv; T[2] += wa.z * vv; T[3] += wa.w * vv;
      T[4] += wb.x * vv; T[5] += wb.y * vv; T[6] += wb.z * vv; T[7] += wb.w * vv;
    }
    float dot = 0.f;
    #pragma unroll
    for (int e = 0; e < 8; ++e)
      dot += T[e] * ut[(size_t)gi * 1024 + e * 128 + b];
    size_t bi = ((size_t)o * 1152 + gi) * 128 + b;
    blogt[bi] += dot;
  }
}

// ---------- softmax over o per (i,b) ----------
__global__ __launch_bounds__(256) void caps_softmax(
    const float* __restrict__ blogt, float* __restrict__ ct)
{
  int idx = blockIdx.x * 256 + threadIdx.x;
  if (idx >= 147456) return;
  const float* bp = blogt + idx;
  float m = -3.4e38f;
  for (int o = 0; o < 100; ++o) m = fmaxf(m, bp[(size_t)o * 147456]);
  float sum = 0.f;
  for (int o = 0; o < 100; ++o) sum += __expf(bp[(size_t)o * 147456] - m);
  float inv = 1.f / sum;
  for (int o = 0; o < 100; ++o)
    ct[(size_t)o * 147456 + idx] = __expf(bp[(size_t)o * 147456] - m) * inv;
}

// ---------- bias + optional relu, in place ----------
__global__ __launch_bounds__(256) void bias_act_k(
    float* __restrict__ C, const float* __restrict__ bias, int N, int total, int relu)
{
  int idx = blockIdx.x * 256 + threadIdx.x;
  if (idx >= total) return;
  float vv = C[idx] + bias[idx % N];
  if (relu) vv = fmaxf(vv, 0.f);
  C[idx] = vv;
}

// ---------- fc3 ----------
__global__ __launch_bounds__(128) void fc3_seed(
    const float* __restrict__ bias, float* __restrict__ out)
{
  int idx = blockIdx.x * 128 + threadIdx.x;
  if (idx < 12800) out[idx] = bias[idx % 100];
}

__global__ __launch_bounds__(128) void fc3_sk(
    const float* __restrict__ A, const float* __restrict__ W,
    float* __restrict__ out)
{
  __shared__ float Al[1024];
  int m = blockIdx.x, z = blockIdx.y, t = threadIdx.x;
  int kbeg = z * 1024;
  const float* ap = A + (size_t)m * 4096 + kbeg;
  for (int l = t; l < 1024; l += 128) Al[l] = ap[l];
  __syncthreads();
  if (t < 100) {
    float acc = 0.f;
    const float* wp = W + (size_t)kbeg * 100 + t;
    #pragma unroll 8
    for (int k = 0; k < 1024; ++k) acc += Al[k] * wp[(size_t)k * 100];
    atomicAdd(out + m * 100 + t, acc);
  }
}

// ============================================================================
extern "C" void kernel_launch(void* const* d_in, const int* in_sizes, int n_in,
                              void* d_out, int out_size, void* d_ws, size_t ws_size,
                              hipStream_t stream)
{
  (void)in_sizes; (void)n_in; (void)out_size; (void)ws_size;
  const float* x   = (const float*)d_in[0];
  const float* cw1 = (const float*)d_in[1];
  const float* cb1 = (const float*)d_in[2];
  const float* cw2 = (const float*)d_in[3];
  const float* cb2 = (const float*)d_in[4];
  const float* cw3 = (const float*)d_in[5];
  const float* cb3 = (const float*)d_in[6];
  const float* pw  = (const float*)d_in[7];
  const float* pb  = (const float*)d_in[8];
  const float* Wc  = (const float*)d_in[9];
  const float* fw1 = (const float*)d_in[10];
  const float* fb1 = (const float*)d_in[11];
  const float* fw2 = (const float*)d_in[12];
  const float* fb2 = (const float*)d_in[13];
  const float* fw3 = (const float*)d_in[14];
  const float* fb3 = (const float*)d_in[15];
  float* ws = (float*)d_ws;

  const size_t OFF_A  = 0;          // h1/h2/h3 ; later blog_t [o,i,b]
  const size_t OFF_B  = 12582912;   // h1p / h2p
  const size_t OFF_U  = 15728640;   // u_t [1152,8,128]
  const size_t OFF_P  = 16908288;   // p [128,256,36]; later v_t [100,16,128]
  const size_t OFF_C  = 18087936;   // c_t [100,1152,128]
  const size_t OFF_V  = 32833536;   // v [128,100,16]
  const size_t OFF_S  = 33038336;   // s [128,100,16]
  const size_t OFF_F1 = 33243136;   // f1 [128,4096]
  const size_t OFF_F2 = 33767424;   // f2 [128,4096]

  float* A     = ws + OFF_A;
  float* Bf    = ws + OFF_B;
  float* ut    = ws + OFF_U;
  float* p     = ws + OFF_P;
  float* vt    = ws + OFF_P;        // reuses p region after squash8
  float* ct    = ws + OFF_C;
  float* v     = ws + OFF_V;
  float* s     = ws + OFF_S;
  float* f1    = ws + OFF_F1;
  float* f2    = ws + OFF_F2;
  float* blogt = ws + OFF_A;

  hipMemsetAsync(p,  0, (size_t)1179648 * 4, stream);
  hipMemsetAsync(f1, 0, (size_t)524288 * 4, stream);
  hipMemsetAsync(f2, 0, (size_t)524288 * 4, stream);

  // Backbone
  conv1_k<<<49152, 256, 0, stream>>>(x, cw1, cb1, A);                 // [128,96,32,32]
  maxpool_k<<<12288, 256, 0, stream>>>(A, Bf, 32);                    // [128,96,16,16]
  convgemm_mfma<96, 16, 1, 16, false><<<dim3(512, 4), 256, 0, stream>>>(Bf, cw2, cb2, A, 256, 1, 0);
  maxpool_k<<<8192, 256, 0, stream>>>(A, Bf, 16);                     // [128,256,8,8]
  convgemm_mfma<256, 8, 1, 8, false><<<dim3(128, 6), 256, 0, stream>>>(Bf, cw3, cb3, A, 384, 1, 0);
  // pcaps split-K x2 (K=3456 -> KC=1728), bias added in squash8
  convgemm_mfma<384, 8, 0, 6, true><<<dim3(72, 4, 2), 256, 0, stream>>>(A, pw, pb, p, 256, 0, 1728);
  squash8_k<<<576, 256, 0, stream>>>(p, pb, ut);                      // u_t [1152,8,128]

  // Dynamic routing (3 iterations), x_hat recomputed on the fly
  hipMemsetAsync(blogt, 0, (size_t)14745600 * 4, stream);
  for (int r = 0; r < 3; ++r) {
    hipMemsetAsync(s, 0, (size_t)204800 * 4, stream);
    if (r == 0) {
      caps_spass<<<dim3(100, 18), 256, 0, stream>>>(Wc, ut, ut /*dummy*/, s, 1);
    } else {
      caps_softmax<<<576, 256, 0, stream>>>(blogt, ct);
      caps_spass<<<dim3(100, 18), 256, 0, stream>>>(Wc, ut, ct, s, 0);
    }
    caps_squash16<<<50, 256, 0, stream>>>(s, v, vt);
    if (r < 2)
      caps_bupdate<<<dim3(100, 18), 256, 0, stream>>>(Wc, ut, vt, blogt);
  }

  // FC head; v is already [128,1600] flat
  fc_mfma<<<dim3(64, 2, 2), 256, 0, stream>>>(v,  fw1, f1, 1600, 4096, 800);
  bias_act_k<<<2048, 256, 0, stream>>>(f1, fb1, 4096, 524288, 1);
  fc_mfma<<<dim3(64, 2, 4), 256, 0, stream>>>(f1, fw2, f2, 4096, 4096, 1024);
  bias_act_k<<<2048, 256, 0, stream>>>(f2, fb2, 4096, 524288, 1);
  fc3_seed<<<100, 128, 0, stream>>>(fb3, (float*)d_out);
  fc3_sk<<<dim3(128, 4), 128, 0, stream>>>(f2, fw3, (float*)d_out);
}

// Round 6
// 1368.094 us; speedup vs baseline: 2.9525x; 1.3319x over previous
//
#include <hip/hip_runtime.h>
#include <cstddef>

// ============================================================================
// AlexCapsNet CIFAR-100 forward. Round 6: routing s-pass rewritten as per-o
// bf16x2 MFMA GEMM (cu staged in LDS as A-frags; W IS the B-frag layout in
// global memory -> zero-broadcast). b-update gets 4-b register blocking to
// amortize wave-uniform W reads. Conv/FC MFMA kernels unchanged from round 5.
// ============================================================================

typedef __attribute__((ext_vector_type(8))) short bf8_t;   // 8 bf16 (4 VGPR)
typedef __attribute__((ext_vector_type(4))) float f4_t;    // 4 fp32 acc

// pack 8 fp32 -> 4 dwords of bf16-hi pairs + 4 dwords of bf16-lo pairs
__device__ inline void cvt_hilo8(const float* f, unsigned* h, unsigned* l)
{
  #pragma unroll
  for (int j = 0; j < 4; ++j) {
    unsigned u0 = __float_as_uint(f[2 * j]);
    unsigned u1 = __float_as_uint(f[2 * j + 1]);
    h[j] = (u0 >> 16) | (u1 & 0xFFFF0000u);
    float r0 = f[2 * j]     - __uint_as_float(u0 & 0xFFFF0000u);
    float r1 = f[2 * j + 1] - __uint_as_float(u1 & 0xFFFF0000u);
    l[j] = (__float_as_uint(r0) >> 16) | (__float_as_uint(r1) & 0xFFFF0000u);
  }
}

// ---------- conv1: direct 3->96 k3 s1 p1 + relu ----------
__global__ __launch_bounds__(256) void conv1_k(
    const float* __restrict__ x, const float* __restrict__ wt,
    const float* __restrict__ bias, float* __restrict__ out)
{
  int idx = blockIdx.x * 256 + threadIdx.x;
  int w = idx & 31, h = (idx >> 5) & 31;
  int t2 = idx >> 10;
  int co = t2 % 96, b = t2 / 96;
  float acc = bias[co];
  #pragma unroll
  for (int ci = 0; ci < 3; ++ci) {
    const float* xp = x + ((size_t)(b * 3 + ci) << 10);
    const float* wp = wt + (size_t)(co * 3 + ci) * 9;
    #pragma unroll
    for (int dh = 0; dh < 3; ++dh) {
      int ih = h + dh - 1;
      if (ih < 0 || ih > 31) continue;
      #pragma unroll
      for (int dw = 0; dw < 3; ++dw) {
        int iw = w + dw - 1;
        if (iw < 0 || iw > 31) continue;
        acc += xp[(ih << 5) + iw] * wp[dh * 3 + dw];
      }
    }
  }
  out[idx] = fmaxf(acc, 0.f);
}

// ---------- maxpool k3 s2 p1 ----------
__global__ __launch_bounds__(256) void maxpool_k(
    const float* __restrict__ in, float* __restrict__ out, int H)
{
  int Ho = H >> 1;
  int idx = blockIdx.x * 256 + threadIdx.x;
  int wo = idx % Ho;
  int t2 = idx / Ho;
  int ho = t2 % Ho;
  int bc = t2 / Ho;
  const float* ip = in + (size_t)bc * H * H;
  float m = -3.4e38f;
  #pragma unroll
  for (int dh = 0; dh < 3; ++dh) {
    int ih = 2 * ho - 1 + dh;
    if (ih < 0 || ih >= H) continue;
    #pragma unroll
    for (int dw = 0; dw < 3; ++dw) {
      int iw = 2 * wo - 1 + dw;
      if (iw < 0 || iw >= H) continue;
      m = fmaxf(m, ip[ih * H + iw]);
    }
  }
  out[idx] = m;
}

// ---------- conv as bf16x2-split MFMA GEMM with on-the-fly im2col ----------
template <int CI, int H, int PAD, int WO, bool SPLIT>
__global__ __launch_bounds__(256) void convgemm_mfma(
    const float* __restrict__ in, const float* __restrict__ wt,
    const float* __restrict__ bias, float* __restrict__ out,
    int CO, int relu, int KC)
{
  constexpr int K = CI * 9;
  constexpr int NPIX = WO * WO;
  __shared__ uint4 Ah[256], Al[256], Bh[256], Bl[256];
  int n0 = blockIdx.x * 64, m0 = blockIdx.y * 64;
  int kbeg = SPLIT ? blockIdx.z * KC : 0;
  int kend = SPLIT ? kbeg + KC : K;
  int t = threadIdx.x;
  int lane = t & 63;
  int wave = __builtin_amdgcn_readfirstlane(t >> 6);
  int wm = wave & 1, wn = wave >> 1;
  int lr = lane & 15, lq = lane >> 4;
  int smA = t >> 2, sgA = t & 3;

  int nn = n0 + lane;
  int bb = nn / NPIX, xy = nn - bb * NPIX;
  int ho = xy / WO, wo = xy - ho * WO;
  int ih0 = ho - PAD, iw0 = wo - PAD;
  const float* inb = in + (size_t)bb * CI * H * H;

  float fa[8], fb[8];
  auto loadA = [&](int k0) {
    const float4* ap = (const float4*)(wt + (size_t)(m0 + smA) * K + k0 + sgA * 8);
    float4 a0 = ap[0], a1 = ap[1];
    fa[0] = a0.x; fa[1] = a0.y; fa[2] = a0.z; fa[3] = a0.w;
    fa[4] = a1.x; fa[5] = a1.y; fa[6] = a1.z; fa[7] = a1.w;
  };
  auto loadB = [&](int k0) {
    int kb = k0 + wave * 8;
    int ci = kb / 9, rr = kb - ci * 9;
    int dh = rr / 3, dw = rr - dh * 3;
    #pragma unroll
    for (int j = 0; j < 8; ++j) {
      int ih = ih0 + dh, iw = iw0 + dw;
      bool ok = (ih >= 0 && ih < H && iw >= 0 && iw < H);
      fb[j] = ok ? inb[(ci * H + ih) * H + iw] : 0.f;
      if (++dw == 3) { dw = 0; if (++dh == 3) { dh = 0; ++ci; } }
    }
  };

  loadA(kbeg); loadB(kbeg);
  f4_t acc[2][2];
  #pragma unroll
  for (int mt = 0; mt < 2; ++mt)
    #pragma unroll
    for (int nt = 0; nt < 2; ++nt) acc[mt][nt] = (f4_t)0.0f;

  for (int k0 = kbeg; k0 < kend; k0 += 32) {
    if (k0 > kbeg) __syncthreads();
    unsigned ha[4], la[4], hb[4], lb[4];
    cvt_hilo8(fa, ha, la);
    cvt_hilo8(fb, hb, lb);
    Ah[sgA * 64 + smA] = make_uint4(ha[0], ha[1], ha[2], ha[3]);
    Al[sgA * 64 + smA] = make_uint4(la[0], la[1], la[2], la[3]);
    Bh[wave * 64 + lane] = make_uint4(hb[0], hb[1], hb[2], hb[3]);
    Bl[wave * 64 + lane] = make_uint4(lb[0], lb[1], lb[2], lb[3]);
    __syncthreads();
    if (k0 + 32 < kend) { loadA(k0 + 32); loadB(k0 + 32); }
    bf8_t av_h[2], av_l[2], bv_h[2], bv_l[2];
    #pragma unroll
    for (int mt = 0; mt < 2; ++mt) {
      int ui = lq * 64 + wm * 32 + mt * 16 + lr;
      av_h[mt] = *(const bf8_t*)&Ah[ui];
      av_l[mt] = *(const bf8_t*)&Al[ui];
    }
    #pragma unroll
    for (int nt = 0; nt < 2; ++nt) {
      int ui = lq * 64 + wn * 32 + nt * 16 + lr;
      bv_h[nt] = *(const bf8_t*)&Bh[ui];
      bv_l[nt] = *(const bf8_t*)&Bl[ui];
    }
    #pragma unroll
    for (int mt = 0; mt < 2; ++mt)
      #pragma unroll
      for (int nt = 0; nt < 2; ++nt) {
        acc[mt][nt] = __builtin_amdgcn_mfma_f32_16x16x32_bf16(av_h[mt], bv_h[nt], acc[mt][nt], 0, 0, 0);
        acc[mt][nt] = __builtin_amdgcn_mfma_f32_16x16x32_bf16(av_h[mt], bv_l[nt], acc[mt][nt], 0, 0, 0);
        acc[mt][nt] = __builtin_amdgcn_mfma_f32_16x16x32_bf16(av_l[mt], bv_h[nt], acc[mt][nt], 0, 0, 0);
      }
  }
  #pragma unroll
  for (int mt = 0; mt < 2; ++mt)
    #pragma unroll
    for (int nt = 0; nt < 2; ++nt) {
      #pragma unroll
      for (int r = 0; r < 4; ++r) {
        int m = m0 + wm * 32 + mt * 16 + lq * 4 + r;
        int n = n0 + wn * 32 + nt * 16 + lr;
        int b = n / NPIX, pxy = n - b * NPIX;
        size_t oidx = ((size_t)b * CO + m) * NPIX + pxy;
        if (SPLIT) {
          atomicAdd(out + oidx, acc[mt][nt][r]);
        } else {
          float vv = acc[mt][nt][r] + bias[m];
          if (relu) vv = fmaxf(vv, 0.f);
          out[oidx] = vv;
        }
      }
    }
}

// ---------- FC as bf16x2-split MFMA GEMM, split-K, atomic partials ----------
__global__ __launch_bounds__(256) void fc_mfma(
    const float* __restrict__ A, const float* __restrict__ W,
    float* __restrict__ C, int K, int N, int KC)
{
  __shared__ uint4 Ah[256], Al[256], Bh[256], Bl[256];
  int n0 = blockIdx.x * 64, m0 = blockIdx.y * 64;
  int kbeg = blockIdx.z * KC, kend = kbeg + KC;
  int t = threadIdx.x;
  int lane = t & 63;
  int wave = __builtin_amdgcn_readfirstlane(t >> 6);
  int wm = wave & 1, wn = wave >> 1;
  int lr = lane & 15, lq = lane >> 4;
  int smA = t >> 2, sgA = t & 3;

  float fa[8], fb[8];
  auto loadA = [&](int k0) {
    const float4* ap = (const float4*)(A + (size_t)(m0 + smA) * K + k0 + sgA * 8);
    float4 a0 = ap[0], a1 = ap[1];
    fa[0] = a0.x; fa[1] = a0.y; fa[2] = a0.z; fa[3] = a0.w;
    fa[4] = a1.x; fa[5] = a1.y; fa[6] = a1.z; fa[7] = a1.w;
  };
  auto loadB = [&](int k0) {
    const float* wp = W + (size_t)(k0 + wave * 8) * N + n0 + lane;
    #pragma unroll
    for (int j = 0; j < 8; ++j) fb[j] = wp[(size_t)j * N];
  };

  loadA(kbeg); loadB(kbeg);
  f4_t acc[2][2];
  #pragma unroll
  for (int mt = 0; mt < 2; ++mt)
    #pragma unroll
    for (int nt = 0; nt < 2; ++nt) acc[mt][nt] = (f4_t)0.0f;

  for (int k0 = kbeg; k0 < kend; k0 += 32) {
    if (k0 > kbeg) __syncthreads();
    unsigned ha[4], la[4], hb[4], lb[4];
    cvt_hilo8(fa, ha, la);
    cvt_hilo8(fb, hb, lb);
    Ah[sgA * 64 + smA] = make_uint4(ha[0], ha[1], ha[2], ha[3]);
    Al[sgA * 64 + smA] = make_uint4(la[0], la[1], la[2], la[3]);
    Bh[wave * 64 + lane] = make_uint4(hb[0], hb[1], hb[2], hb[3]);
    Bl[wave * 64 + lane] = make_uint4(lb[0], lb[1], lb[2], lb[3]);
    __syncthreads();
    if (k0 + 32 < kend) { loadA(k0 + 32); loadB(k0 + 32); }
    bf8_t av_h[2], av_l[2], bv_h[2], bv_l[2];
    #pragma unroll
    for (int mt = 0; mt < 2; ++mt) {
      int ui = lq * 64 + wm * 32 + mt * 16 + lr;
      av_h[mt] = *(const bf8_t*)&Ah[ui];
      av_l[mt] = *(const bf8_t*)&Al[ui];
    }
    #pragma unroll
    for (int nt = 0; nt < 2; ++nt) {
      int ui = lq * 64 + wn * 32 + nt * 16 + lr;
      bv_h[nt] = *(const bf8_t*)&Bh[ui];
      bv_l[nt] = *(const bf8_t*)&Bl[ui];
    }
    #pragma unroll
    for (int mt = 0; mt < 2; ++mt)
      #pragma unroll
      for (int nt = 0; nt < 2; ++nt) {
        acc[mt][nt] = __builtin_amdgcn_mfma_f32_16x16x32_bf16(av_h[mt], bv_h[nt], acc[mt][nt], 0, 0, 0);
        acc[mt][nt] = __builtin_amdgcn_mfma_f32_16x16x32_bf16(av_h[mt], bv_l[nt], acc[mt][nt], 0, 0, 0);
        acc[mt][nt] = __builtin_amdgcn_mfma_f32_16x16x32_bf16(av_l[mt], bv_h[nt], acc[mt][nt], 0, 0, 0);
      }
  }
  #pragma unroll
  for (int mt = 0; mt < 2; ++mt)
    #pragma unroll
    for (int nt = 0; nt < 2; ++nt) {
      #pragma unroll
      for (int r = 0; r < 4; ++r) {
        int m = m0 + wm * 32 + mt * 16 + lq * 4 + r;
        int n = n0 + wn * 32 + nt * 16 + lr;
        atomicAdd(C + (size_t)m * N + n, acc[mt][nt][r]);
      }
    }
}

// ---------- squash8 + pcaps bias; p[b,256,36] partials -> u_t[i,e,b] ----------
__global__ __launch_bounds__(256) void squash8_k(
    const float* __restrict__ p, const float* __restrict__ pb,
    float* __restrict__ ut)
{
  int idx = blockIdx.x * 256 + threadIdx.x;
  if (idx >= 147456) return;
  int b = idx & 127, i = idx >> 7;
  const float4* pp = (const float4*)(p + ((size_t)b * 1152 + i) * 8);
  float4 a = pp[0], bb = pp[1];
  float pv[8] = {a.x, a.y, a.z, a.w, bb.x, bb.y, bb.z, bb.w};
  int f0 = i * 8;
  #pragma unroll
  for (int e = 0; e < 8; ++e) pv[e] += pb[(f0 + e) / 36];
  float n2 = 0.f;
  #pragma unroll
  for (int e = 0; e < 8; ++e) n2 += pv[e] * pv[e];
  float sc = (n2 / (1.f + n2)) * rsqrtf(n2 + 1e-8f);
  #pragma unroll
  for (int e = 0; e < 8; ++e)
    ut[(size_t)i * 1024 + e * 128 + b] = pv[e] * sc;
}

// ---------- squash16: s[b,o,16] -> v[b,o,16] + v_t[o,d,b] ----------
__global__ __launch_bounds__(256) void caps_squash16(
    const float* __restrict__ s, float* __restrict__ v, float* __restrict__ vt)
{
  int idx = blockIdx.x * 256 + threadIdx.x;
  if (idx >= 12800) return;
  int b = idx / 100, o = idx % 100;
  const float4* sp = (const float4*)(s + (size_t)idx * 16);
  float4 a = sp[0], bb = sp[1], c = sp[2], d = sp[3];
  float n2 = a.x * a.x + a.y * a.y + a.z * a.z + a.w * a.w +
             bb.x * bb.x + bb.y * bb.y + bb.z * bb.z + bb.w * bb.w +
             c.x * c.x + c.y * c.y + c.z * c.z + c.w * c.w +
             d.x * d.x + d.y * d.y + d.z * d.z + d.w * d.w;
  float sc = (n2 / (1.f + n2)) * rsqrtf(n2 + 1e-8f);
  float vv[16] = {a.x, a.y, a.z, a.w, bb.x, bb.y, bb.z, bb.w,
                  c.x, c.y, c.z, c.w, d.x, d.y, d.z, d.w};
  float4* vp = (float4*)(v + (size_t)idx * 16);
  float4 o0 = {vv[0] * sc, vv[1] * sc, vv[2] * sc, vv[3] * sc};
  float4 o1 = {vv[4] * sc, vv[5] * sc, vv[6] * sc, vv[7] * sc};
  float4 o2 = {vv[8] * sc, vv[9] * sc, vv[10] * sc, vv[11] * sc};
  float4 o3 = {vv[12] * sc, vv[13] * sc, vv[14] * sc, vv[15] * sc};
  vp[0] = o0; vp[1] = o1; vp[2] = o2; vp[3] = o3;
  #pragma unroll
  for (int dd = 0; dd < 16; ++dd)
    vt[((size_t)o * 16 + dd) * 128 + b] = vv[dd] * sc;
}

// ---------- routing s-pass as per-o MFMA GEMM ----------
// s[b,d] += sum_{(i,e)} cu[b,(i,e)] * W[o,(i,e),d];  cu = c*u staged in LDS as
// bf16 hi/lo A-frags; W[o][i][d][e] read directly from global in B-frag order
// (lane n=d reads 8 contiguous e's). grid (o=100, ks=8): K-chunk 1152 = 36
// k-steps of 32 (4 i x 8 e). 8 m-tiles of b; wave w owns {w, w+4}.
__global__ __launch_bounds__(256) void caps_spass_mfma(
    const float* __restrict__ W, const float* __restrict__ ut,
    const float* __restrict__ ct, float* __restrict__ s, int uniform)
{
  __shared__ uint4 Ah[512], Al[512];               // [quad(4)][b(128)] 8KB each
  int o = blockIdx.x, ks = blockIdx.y;
  int t = threadIdx.x;
  int lane = t & 63;
  int wave = __builtin_amdgcn_readfirstlane(t >> 6);
  int lr = lane & 15, lq = lane >> 4;
  int b = t & 127, half = t >> 7;                  // staging role
  int i0 = ks * 144;

  float fu[16], fc[2], fw[8];
  auto loadUC = [&](int j) {
    int ib = i0 + j * 4 + half * 2;
    #pragma unroll
    for (int q = 0; q < 2; ++q) {
      int i = ib + q;
      #pragma unroll
      for (int e = 0; e < 8; ++e)
        fu[q * 8 + e] = ut[(size_t)i * 1024 + e * 128 + b];   // coalesced
      fc[q] = uniform ? 0.01f : ct[((size_t)o * 1152 + i) * 128 + b];
    }
  };
  auto loadW = [&](int j) {
    int i = i0 + j * 4 + lq;
    const float4* wp = (const float4*)(W + (((size_t)o * 1152 + i) * 16 + lr) * 8);
    float4 w0 = wp[0], w1 = wp[1];
    fw[0] = w0.x; fw[1] = w0.y; fw[2] = w0.z; fw[3] = w0.w;
    fw[4] = w1.x; fw[5] = w1.y; fw[6] = w1.z; fw[7] = w1.w;
  };

  loadUC(0); loadW(0);
  f4_t acc[2];
  acc[0] = (f4_t)0.0f; acc[1] = (f4_t)0.0f;

  for (int j = 0; j < 36; ++j) {
    float cu[16];
    #pragma unroll
    for (int q = 0; q < 2; ++q)
      #pragma unroll
      for (int e = 0; e < 8; ++e)
        cu[q * 8 + e] = fc[q] * fu[q * 8 + e];
    unsigned h0[4], l0[4], h1[4], l1[4], wh[4], wl[4];
    cvt_hilo8(cu, h0, l0);
    cvt_hilo8(cu + 8, h1, l1);
    cvt_hilo8(fw, wh, wl);                          // current W split (before prefetch)
    uint4 uwh = make_uint4(wh[0], wh[1], wh[2], wh[3]);
    uint4 uwl = make_uint4(wl[0], wl[1], wl[2], wl[3]);
    bf8_t bfh = *(const bf8_t*)&uwh;
    bf8_t bfl = *(const bf8_t*)&uwl;
    if (j > 0) __syncthreads();
    Ah[(half * 2 + 0) * 128 + b] = make_uint4(h0[0], h0[1], h0[2], h0[3]);
    Al[(half * 2 + 0) * 128 + b] = make_uint4(l0[0], l0[1], l0[2], l0[3]);
    Ah[(half * 2 + 1) * 128 + b] = make_uint4(h1[0], h1[1], h1[2], h1[3]);
    Al[(half * 2 + 1) * 128 + b] = make_uint4(l1[0], l1[1], l1[2], l1[3]);
    __syncthreads();
    if (j + 1 < 36) { loadUC(j + 1); loadW(j + 1); }
    #pragma unroll
    for (int mt = 0; mt < 2; ++mt) {
      int bidx = wave * 16 + mt * 64 + lr;
      bf8_t avh = *(const bf8_t*)&Ah[lq * 128 + bidx];
      bf8_t avl = *(const bf8_t*)&Al[lq * 128 + bidx];
      acc[mt] = __builtin_amdgcn_mfma_f32_16x16x32_bf16(avh, bfh, acc[mt], 0, 0, 0);
      acc[mt] = __builtin_amdgcn_mfma_f32_16x16x32_bf16(avh, bfl, acc[mt], 0, 0, 0);
      acc[mt] = __builtin_amdgcn_mfma_f32_16x16x32_bf16(avl, bfh, acc[mt], 0, 0, 0);
    }
  }
  // D layout: col(d)=lane&15, row(b)=lq*4+r
  #pragma unroll
  for (int mt = 0; mt < 2; ++mt)
    #pragma unroll
    for (int r = 0; r < 4; ++r) {
      int bb = wave * 16 + mt * 64 + lq * 4 + r;
      atomicAdd(s + ((size_t)bb * 100 + o) * 16 + lr, acc[mt][r]);
    }
}

// ---------- routing b-update, 4-b register blocking ----------
// blog_t[o,i,b] += sum_e u[b,i,e] * (sum_d W[o,i,d,e] v[b,o,d])
__global__ __launch_bounds__(256) void caps_bupdate(
    const float* __restrict__ W, const float* __restrict__ ut,
    const float* __restrict__ vt, float* __restrict__ blogt)
{
  __shared__ __align__(16) float Wl[8192];
  int o = blockIdx.x, ic = blockIdx.y, t = threadIdx.x;
  const float4* Wg = (const float4*)(W + ((size_t)o * 1152 + (size_t)ic * 64) * 128);
  float4* Wl4 = (float4*)Wl;
  for (int l = t; l < 2048; l += 256) Wl4[l] = Wg[l];
  int bq = t & 31;                                  // b = bq + 32*bi
  int ig = t >> 5;                                  // i-subset: i = ic*64 + ig*8 + jj
  float vr[4][16];
  #pragma unroll
  for (int bi = 0; bi < 4; ++bi) {
    int b = bq + 32 * bi;
    #pragma unroll
    for (int d = 0; d < 16; ++d)
      vr[bi][d] = vt[((size_t)o * 16 + d) * 128 + b];
  }
  __syncthreads();
  for (int jj = 0; jj < 8; ++jj) {
    int li = ig * 8 + jj;
    int gi = ic * 64 + li;
    const float4* Wr = (const float4*)(Wl + li * 128);
    float T[4][8] = {};
    #pragma unroll
    for (int d = 0; d < 16; ++d) {
      float4 wa = Wr[d * 2], wb = Wr[d * 2 + 1];    // 2-way broadcast per wave
      #pragma unroll
      for (int bi = 0; bi < 4; ++bi) {
        float vv = vr[bi][d];
        T[bi][0] += wa.x * vv; T[bi][1] += wa.y * vv; T[bi][2] += wa.z * vv; T[bi][3] += wa.w * vv;
        T[bi][4] += wb.x * vv; T[bi][5] += wb.y * vv; T[bi][6] += wb.z * vv; T[bi][7] += wb.w * vv;
      }
    }
    #pragma unroll
    for (int bi = 0; bi < 4; ++bi) {
      int b = bq + 32 * bi;
      float dot = 0.f;
      #pragma unroll
      for (int e = 0; e < 8; ++e)
        dot += T[bi][e] * ut[(size_t)gi * 1024 + e * 128 + b];
      blogt[((size_t)o * 1152 + gi) * 128 + b] += dot;
    }
  }
}

// ---------- softmax over o per (i,b), transposed layouts ----------
__global__ __launch_bounds__(256) void caps_softmax(
    const float* __restrict__ blogt, float* __restrict__ ct)
{
  int idx = blockIdx.x * 256 + threadIdx.x;
  if (idx >= 147456) return;
  const float* bp = blogt + idx;
  float m = -3.4e38f;
  for (int o = 0; o < 100; ++o) m = fmaxf(m, bp[(size_t)o * 147456]);
  float sum = 0.f;
  for (int o = 0; o < 100; ++o) sum += __expf(bp[(size_t)o * 147456] - m);
  float inv = 1.f / sum;
  for (int o = 0; o < 100; ++o)
    ct[(size_t)o * 147456 + idx] = __expf(bp[(size_t)o * 147456] - m) * inv;
}

// ---------- bias + optional relu, in place ----------
__global__ __launch_bounds__(256) void bias_act_k(
    float* __restrict__ C, const float* __restrict__ bias, int N, int total, int relu)
{
  int idx = blockIdx.x * 256 + threadIdx.x;
  if (idx >= total) return;
  float vv = C[idx] + bias[idx % N];
  if (relu) vv = fmaxf(vv, 0.f);
  C[idx] = vv;
}

// ---------- fc3 ----------
__global__ __launch_bounds__(128) void fc3_seed(
    const float* __restrict__ bias, float* __restrict__ out)
{
  int idx = blockIdx.x * 128 + threadIdx.x;
  if (idx < 12800) out[idx] = bias[idx % 100];
}

__global__ __launch_bounds__(128) void fc3_sk(
    const float* __restrict__ A, const float* __restrict__ W,
    float* __restrict__ out)
{
  __shared__ float Al[1024];
  int m = blockIdx.x, z = blockIdx.y, t = threadIdx.x;
  int kbeg = z * 1024;
  const float* ap = A + (size_t)m * 4096 + kbeg;
  for (int l = t; l < 1024; l += 128) Al[l] = ap[l];
  __syncthreads();
  if (t < 100) {
    float acc = 0.f;
    const float* wp = W + (size_t)kbeg * 100 + t;
    #pragma unroll 8
    for (int k = 0; k < 1024; ++k) acc += Al[k] * wp[(size_t)k * 100];
    atomicAdd(out + m * 100 + t, acc);
  }
}

// ============================================================================
extern "C" void kernel_launch(void* const* d_in, const int* in_sizes, int n_in,
                              void* d_out, int out_size, void* d_ws, size_t ws_size,
                              hipStream_t stream)
{
  (void)in_sizes; (void)n_in; (void)out_size; (void)ws_size;
  const float* x   = (const float*)d_in[0];
  const float* cw1 = (const float*)d_in[1];
  const float* cb1 = (const float*)d_in[2];
  const float* cw2 = (const float*)d_in[3];
  const float* cb2 = (const float*)d_in[4];
  const float* cw3 = (const float*)d_in[5];
  const float* cb3 = (const float*)d_in[6];
  const float* pw  = (const float*)d_in[7];
  const float* pb  = (const float*)d_in[8];
  const float* Wc  = (const float*)d_in[9];
  const float* fw1 = (const float*)d_in[10];
  const float* fb1 = (const float*)d_in[11];
  const float* fw2 = (const float*)d_in[12];
  const float* fb2 = (const float*)d_in[13];
  const float* fw3 = (const float*)d_in[14];
  const float* fb3 = (const float*)d_in[15];
  float* ws = (float*)d_ws;

  const size_t OFF_A  = 0;          // h1/h2/h3 ; later blog_t [o,i,b]
  const size_t OFF_B  = 12582912;   // h1p / h2p
  const size_t OFF_U  = 15728640;   // u_t [1152,8,128]
  const size_t OFF_P  = 16908288;   // p [128,256,36]; later v_t [100,16,128]
  const size_t OFF_C  = 18087936;   // c_t [100,1152,128]
  const size_t OFF_V  = 32833536;   // v [128,100,16]
  const size_t OFF_S  = 33038336;   // s [128,100,16]
  const size_t OFF_F1 = 33243136;   // f1 [128,4096]
  const size_t OFF_F2 = 33767424;   // f2 [128,4096]

  float* A     = ws + OFF_A;
  float* Bf    = ws + OFF_B;
  float* ut    = ws + OFF_U;
  float* p     = ws + OFF_P;
  float* vt    = ws + OFF_P;        // reuses p region after squash8
  float* ct    = ws + OFF_C;
  float* v     = ws + OFF_V;
  float* s     = ws + OFF_S;
  float* f1    = ws + OFF_F1;
  float* f2    = ws + OFF_F2;
  float* blogt = ws + OFF_A;

  hipMemsetAsync(p,  0, (size_t)1179648 * 4, stream);
  hipMemsetAsync(f1, 0, (size_t)524288 * 4, stream);
  hipMemsetAsync(f2, 0, (size_t)524288 * 4, stream);

  // Backbone
  conv1_k<<<49152, 256, 0, stream>>>(x, cw1, cb1, A);                 // [128,96,32,32]
  maxpool_k<<<12288, 256, 0, stream>>>(A, Bf, 32);                    // [128,96,16,16]
  convgemm_mfma<96, 16, 1, 16, false><<<dim3(512, 4), 256, 0, stream>>>(Bf, cw2, cb2, A, 256, 1, 0);
  maxpool_k<<<8192, 256, 0, stream>>>(A, Bf, 16);                     // [128,256,8,8]
  convgemm_mfma<256, 8, 1, 8, false><<<dim3(128, 6), 256, 0, stream>>>(Bf, cw3, cb3, A, 384, 1, 0);
  convgemm_mfma<384, 8, 0, 6, true><<<dim3(72, 4, 2), 256, 0, stream>>>(A, pw, pb, p, 256, 0, 1728);
  squash8_k<<<576, 256, 0, stream>>>(p, pb, ut);                      // u_t [1152,8,128]

  // Dynamic routing (3 iterations), x_hat recomputed on the fly via MFMA
  hipMemsetAsync(blogt, 0, (size_t)14745600 * 4, stream);
  for (int r = 0; r < 3; ++r) {
    hipMemsetAsync(s, 0, (size_t)204800 * 4, stream);
    if (r == 0) {
      caps_spass_mfma<<<dim3(100, 8), 256, 0, stream>>>(Wc, ut, ut /*dummy*/, s, 1);
    } else {
      caps_softmax<<<576, 256, 0, stream>>>(blogt, ct);
      caps_spass_mfma<<<dim3(100, 8), 256, 0, stream>>>(Wc, ut, ct, s, 0);
    }
    caps_squash16<<<50, 256, 0, stream>>>(s, v, vt);
    if (r < 2)
      caps_bupdate<<<dim3(100, 18), 256, 0, stream>>>(Wc, ut, vt, blogt);
  }

  // FC head; v is already [128,1600] flat
  fc_mfma<<<dim3(64, 2, 2), 256, 0, stream>>>(v,  fw1, f1, 1600, 4096, 800);
  bias_act_k<<<2048, 256, 0, stream>>>(f1, fb1, 4096, 524288, 1);
  fc_mfma<<<dim3(64, 2, 4), 256, 0, stream>>>(f1, fw2, f2, 4096, 4096, 1024);
  bias_act_k<<<2048, 256, 0, stream>>>(f2, fb2, 4096, 524288, 1);
  fc3_seed<<<100, 128, 0, stream>>>(fb3, (float*)d_out);
  fc3_sk<<<dim3(128, 4), 128, 0, stream>>>(f2, fw3, (float*)d_out);
}